// Round 4
// baseline (613.708 us; speedup 1.0000x reference)
//
#include <hip/hip_runtime.h>

#define NFEAT 128
#define NHID  64
#define NOUT  21
#define BSH   7            // bucket shift: 128 nodes / bucket
#define BCAP  8192         // max edges LDS-sorted per bucket

typedef unsigned int uint;

// bf16 pack/unpack (RTN-even)
__device__ inline uint packbf2(float a, float b) {
    uint ua = __float_as_uint(a), ub = __float_as_uint(b);
    ua = (ua + 0x7FFFu + ((ua >> 16) & 1u)) >> 16;
    ub = (ub + 0x7FFFu + ((ub >> 16) & 1u)) >> 16;
    return ua | (ub << 16);
}
__device__ inline float bflo(uint v) { return __uint_as_float(v << 16); }
__device__ inline float bfhi(uint v) { return __uint_as_float(v & 0xffff0000u); }

// ================= CSR build =================

__global__ __launch_bounds__(256) void k_count(const int* __restrict__ dst, int* cnt, int E) {
    int e = blockIdx.x * 256 + threadIdx.x;
    if (e < E) atomicAdd(&cnt[dst[e]], 1);
}

// block-local exclusive scan (1024 elems/block) + dinv = rsqrt(deg+1)
__global__ __launch_bounds__(256) void k_scan1(const int* __restrict__ cnt, int* __restrict__ rowptr,
                                               int* __restrict__ bsum, float* __restrict__ dinv, int N) {
    __shared__ int sh[256];
    int tid = threadIdx.x;
    int base = blockIdx.x * 1024 + tid * 4;
    int v[4]; int s = 0;
#pragma unroll
    for (int j = 0; j < 4; ++j) {
        v[j] = (base + j < N) ? cnt[base + j] : 0;
        if (base + j < N) dinv[base + j] = rsqrtf((float)(v[j] + 1));
        s += v[j];
    }
    sh[tid] = s; __syncthreads();
    for (int off = 1; off < 256; off <<= 1) {
        int t = (tid >= off) ? sh[tid - off] : 0;
        __syncthreads();
        sh[tid] += t;
        __syncthreads();
    }
    int run = sh[tid] - s;
#pragma unroll
    for (int j = 0; j < 4; ++j) { if (base + j < N) rowptr[base + j] = run; run += v[j]; }
    if (tid == 255) bsum[blockIdx.x] = sh[255];
}

__global__ __launch_bounds__(128) void k_scan2(int* bsum, int nb) {
    __shared__ int sh[128];
    int tid = threadIdx.x;
    int v = (tid < nb) ? bsum[tid] : 0;
    sh[tid] = v; __syncthreads();
    for (int off = 1; off < 128; off <<= 1) {
        int t = (tid >= off) ? sh[tid - off] : 0;
        __syncthreads();
        sh[tid] += t;
        __syncthreads();
    }
    if (tid < nb) bsum[tid] = sh[tid] - v;
}

// finalize rowptr; fill = rowptr (fallback cursors); bfill[b] = rowptr[b<<BSH]; rowptr[N]=E
__global__ __launch_bounds__(256) void k_scan3(int* __restrict__ rowptr, int* __restrict__ fill,
                                               int* __restrict__ bfill, const int* __restrict__ bsum,
                                               int N, int E) {
    int tid = threadIdx.x;
    int base = blockIdx.x * 1024 + tid * 4;
    int add = bsum[blockIdx.x];
#pragma unroll
    for (int j = 0; j < 4; ++j) {
        int idx = base + j;
        if (idx < N) {
            int r = rowptr[idx] + add;
            rowptr[idx] = r;
            fill[idx] = r;
            if ((idx & ((1 << BSH) - 1)) == 0) bfill[idx >> BSH] = r;
        }
    }
    if (blockIdx.x == 0 && tid == 0) rowptr[N] = E;
}

// append packed (localdst, src) record to the dst's coarse bucket
__global__ __launch_bounds__(256) void k_bscatter(const int* __restrict__ src, const int* __restrict__ dst,
                                                  int* __restrict__ bfill, uint* __restrict__ ebuf, int E) {
    int e = blockIdx.x * 256 + threadIdx.x;
    if (e >= E) return;
    int d = dst[e];
    int pos = atomicAdd(&bfill[d >> BSH], 1);
    ebuf[pos] = ((uint)(d & ((1 << BSH) - 1)) << 17) | (uint)src[e];
}

// per-bucket LDS counting sort -> esrc (dst-grouped src ids), coalesced output
__global__ __launch_bounds__(256) void k_bsort(const int* __restrict__ rowptr, const uint* __restrict__ ebuf,
                                               int* __restrict__ esrc, int* __restrict__ fill, int N) {
    __shared__ int  lcur[1 << BSH];
    __shared__ int  lsort[BCAP];
    int b = blockIdx.x;
    int tid = threadIdx.x;
    int nb0 = b << BSH;
    int nend = min(nb0 + (1 << BSH), N);
    int bbase = rowptr[nb0];
    int bend  = rowptr[nend];
    int cnt_b = bend - bbase;
    if (cnt_b <= 0) return;
    if (cnt_b <= BCAP) {
        if (tid < (1 << BSH)) {
            int node = nb0 + tid;
            lcur[tid] = (node < N ? rowptr[node] : bend) - bbase;
        }
        __syncthreads();
        for (int i = tid; i < cnt_b; i += 256) {
            uint v = ebuf[bbase + i];
            int pos = atomicAdd(&lcur[v >> 17], 1);
            lsort[pos] = (int)(v & 0x1FFFFu);
        }
        __syncthreads();
        for (int i = tid; i < cnt_b; i += 256) esrc[bbase + i] = lsort[i];
    } else {
        // oversized bucket (adversarial input): global per-node cursors
        for (int i = tid; i < cnt_b; i += 256) {
            uint v = ebuf[bbase + i];
            int pos = atomicAdd(&fill[nb0 + (int)(v >> 17)], 1);
            esrc[pos] = (int)(v & 0x1FFFFu);
        }
    }
}

// general-N fallback (no packing): direct scatter with per-node cursors
__global__ __launch_bounds__(256) void k_scatter_direct(const int* __restrict__ src, const int* __restrict__ dst,
                                                        int* __restrict__ fill, int* __restrict__ esrc, int E) {
    int e = blockIdx.x * 256 + threadIdx.x;
    if (e >= E) return;
    int pos = atomicAdd(&fill[dst[e]], 1);
    esrc[pos] = src[e];
}

// ===== GEMM1: h' = dinv * (x @ W1), stored packed bf16 [N][32 uints] =====

__global__ __launch_bounds__(256) void k_gemm1(const float* __restrict__ x, const float* __restrict__ W1,
                                               const float* __restrict__ dinv, uint* __restrict__ hb, int N) {
    __shared__ float Ws[NFEAT * NHID];  // 32 KB
    int tid = threadIdx.x;
#pragma unroll
    for (int i = 0; i < 8; ++i) {
        int idx = (tid + i * 256) * 4;
        *(float4*)&Ws[idx] = *(const float4*)&W1[idx];
    }
    __syncthreads();
    int row = blockIdx.x * 64 + (tid >> 2);
    if (row >= N) return;
    int cg = (tid & 3) * 16;
    float acc[16];
#pragma unroll
    for (int j = 0; j < 16; ++j) acc[j] = 0.f;
    const float* xr = x + (size_t)row * NFEAT;
#pragma unroll 4
    for (int k4 = 0; k4 < NFEAT / 4; ++k4) {
        float4 xv = *(const float4*)&xr[k4 * 4];
        float xs[4] = {xv.x, xv.y, xv.z, xv.w};
#pragma unroll
        for (int kk = 0; kk < 4; ++kk) {
            const float* wrow = &Ws[(k4 * 4 + kk) * NHID + cg];
#pragma unroll
            for (int j4 = 0; j4 < 4; ++j4) {
                float4 w = *(const float4*)&wrow[j4 * 4];
                acc[j4 * 4 + 0] = fmaf(xs[kk], w.x, acc[j4 * 4 + 0]);
                acc[j4 * 4 + 1] = fmaf(xs[kk], w.y, acc[j4 * 4 + 1]);
                acc[j4 * 4 + 2] = fmaf(xs[kk], w.z, acc[j4 * 4 + 2]);
                acc[j4 * 4 + 3] = fmaf(xs[kk], w.w, acc[j4 * 4 + 3]);
            }
        }
    }
    float dv = dinv[row];
    uint up[8];
#pragma unroll
    for (int j = 0; j < 8; ++j) up[j] = packbf2(acc[2 * j] * dv, acc[2 * j + 1] * dv);
    uint* hr = hb + (size_t)row * 32 + (tid & 3) * 8;
    ((uint4*)hr)[0] = make_uint4(up[0], up[1], up[2], up[3]);
    ((uint4*)hr)[1] = make_uint4(up[4], up[5], up[6], up[7]);
}

// ===== agg1: o1[d] = relu(b1 + dv_d*(h'[d] + sum_e h'[src_e])), f32 out =====

__global__ __launch_bounds__(256) void k_agg1(const int* __restrict__ rowptr, const int* __restrict__ esrc,
                                              const uint* __restrict__ hb, const float* __restrict__ dinv,
                                              const float* __restrict__ b1, float* __restrict__ o1, int N) {
    int tid = threadIdx.x;
    int node = blockIdx.x * 4 + (tid >> 6);
    if (node >= N) return;
    int lane = tid & 63;
    int half = lane >> 5;
    int c = lane & 31;
    uint sv = hb[(size_t)node * 32 + c];
    float ax = half ? 0.f : bflo(sv);
    float ay = half ? 0.f : bfhi(sv);
    int beg = rowptr[node], end = rowptr[node + 1];
    int i = beg + half;
    for (; i + 2 < end; i += 4) {
        int s0 = esrc[i], s1 = esrc[i + 2];
        uint v0 = hb[(size_t)s0 * 32 + c];
        uint v1 = hb[(size_t)s1 * 32 + c];
        ax += bflo(v0); ay += bfhi(v0);
        ax += bflo(v1); ay += bfhi(v1);
    }
    if (i < end) {
        uint v = hb[(size_t)esrc[i] * 32 + c];
        ax += bflo(v); ay += bfhi(v);
    }
    ax += __shfl_xor(ax, 32);
    ay += __shfl_xor(ay, 32);
    if (!half) {
        float dv = dinv[node];
        float2 bv = ((const float2*)b1)[c];
        float2 r;
        r.x = fmaxf(fmaf(ax, dv, bv.x), 0.f);
        r.y = fmaxf(fmaf(ay, dv, bv.y), 0.f);
        ((float2*)(o1 + (size_t)node * NHID))[c] = r;
    }
}

// ===== GEMM2: h2' = dinv * (o1 @ W2), packed bf16 padded to 24 feats =====

__global__ __launch_bounds__(128) void k_gemm2(const float* __restrict__ o1, const float* __restrict__ W2,
                                               const float* __restrict__ dinv, uint* __restrict__ h2b, int N) {
    __shared__ float rs[128 * 65];
    __shared__ float Ws[NHID * NOUT];
    int tid = threadIdx.x;
    for (int i = tid; i < NHID * NOUT; i += 128) Ws[i] = W2[i];
    int base = blockIdx.x * 128;
#pragma unroll
    for (int i = 0; i < 16; ++i) {
        int idx = tid + i * 128;
        int row = idx >> 4;
        int f4 = (idx & 15) * 4;
        int grow = base + row;
        float4 v = make_float4(0.f, 0.f, 0.f, 0.f);
        if (grow < N) v = *(const float4*)&o1[(size_t)grow * NHID + f4];
        float* d = &rs[row * 65 + f4];
        d[0] = v.x; d[1] = v.y; d[2] = v.z; d[3] = v.w;
    }
    __syncthreads();
    int row = base + tid;
    if (row >= N) return;
    float acc[NOUT];
#pragma unroll
    for (int j = 0; j < NOUT; ++j) acc[j] = 0.f;
    for (int k = 0; k < NHID; ++k) {
        float av = rs[tid * 65 + k];
#pragma unroll
        for (int j = 0; j < NOUT; ++j) acc[j] = fmaf(av, Ws[k * NOUT + j], acc[j]);
    }
    float dv = dinv[row];
    uint up[12];
#pragma unroll
    for (int j = 0; j < 10; ++j) up[j] = packbf2(acc[2 * j] * dv, acc[2 * j + 1] * dv);
    up[10] = packbf2(acc[20] * dv, 0.f);
    up[11] = 0u;
    uint* hr = h2b + (size_t)row * 12;
    ((uint4*)hr)[0] = make_uint4(up[0], up[1], up[2], up[3]);
    ((uint4*)hr)[1] = make_uint4(up[4], up[5], up[6], up[7]);
    ((uint4*)hr)[2] = make_uint4(up[8], up[9], up[10], up[11]);
}

// ===== agg2: out[d] = b2 + dv_d*(h2'[d] + sum_e h2'[src_e]) =====

__global__ __launch_bounds__(256) void k_agg2(const int* __restrict__ rowptr, const int* __restrict__ esrc,
                                              const uint* __restrict__ h2b, const float* __restrict__ dinv,
                                              const float* __restrict__ b2, float* __restrict__ out, int N) {
    int tid = threadIdx.x;
    int node = blockIdx.x * 64 + (tid >> 2);
    if (node >= N) return;
    int q = tid & 3;
    const uint* sp = h2b + (size_t)node * 12 + q * 3;
    uint u0 = sp[0], u1 = sp[1], u2 = sp[2];
    float a0 = bflo(u0), a1 = bfhi(u0), a2 = bflo(u1), a3 = bfhi(u1), a4 = bflo(u2), a5 = bfhi(u2);
    int beg = rowptr[node], end = rowptr[node + 1];
    int i = beg;
    for (; i + 1 < end; i += 2) {
        const uint* p0 = h2b + (size_t)esrc[i] * 12 + q * 3;
        const uint* p1 = h2b + (size_t)esrc[i + 1] * 12 + q * 3;
        uint x0 = p0[0], x1 = p0[1], x2 = p0[2];
        uint y0 = p1[0], y1 = p1[1], y2 = p1[2];
        a0 += bflo(x0) + bflo(y0); a1 += bfhi(x0) + bfhi(y0);
        a2 += bflo(x1) + bflo(y1); a3 += bfhi(x1) + bfhi(y1);
        a4 += bflo(x2) + bflo(y2); a5 += bfhi(x2) + bfhi(y2);
    }
    if (i < end) {
        const uint* p0 = h2b + (size_t)esrc[i] * 12 + q * 3;
        uint x0 = p0[0], x1 = p0[1], x2 = p0[2];
        a0 += bflo(x0); a1 += bfhi(x0);
        a2 += bflo(x1); a3 += bfhi(x1);
        a4 += bflo(x2); a5 += bfhi(x2);
    }
    float dv = dinv[node];
    float* orow = out + (size_t)node * NOUT;
    int col = q * 6;
    float av[6] = {a0, a1, a2, a3, a4, a5};
#pragma unroll
    for (int j = 0; j < 6; ++j)
        if (col + j < NOUT) orow[col + j] = fmaf(dv, av[j], b2[col + j]);
}

// ================= launch =================

extern "C" void kernel_launch(void* const* d_in, const int* in_sizes, int n_in,
                              void* d_out, int out_size, void* d_ws, size_t ws_size,
                              hipStream_t stream) {
    const float* x  = (const float*)d_in[0];
    const int*   ei = (const int*)d_in[1];
    const float* W1 = (const float*)d_in[2];
    const float* b1 = (const float*)d_in[3];
    const float* W2 = (const float*)d_in[4];
    const float* b2 = (const float*)d_in[5];
    float* out = (float*)d_out;

    int N = in_sizes[0] / NFEAT;
    int E = in_sizes[1] / 2;
    const int* src = ei;
    const int* dst = ei + E;
    int NB = (N + (1 << BSH) - 1) >> BSH;

    char* p = (char*)d_ws;
    auto alloc = [&](size_t bytes) { void* r = (void*)p; p += (bytes + 255) & ~(size_t)255; return r; };
    int*   cnt    = (int*)alloc((size_t)N * 4);
    int*   rowptr = (int*)alloc((size_t)(N + 1) * 4);
    int*   fill   = (int*)alloc((size_t)N * 4);
    int*   bfill  = (int*)alloc((size_t)NB * 4);
    int*   bsum   = (int*)alloc(128 * 4);
    uint*  ebuf   = (uint*)alloc((size_t)E * 4);         // bucket-sorted packed (ldst,src)
    int*   esrc   = (int*)alloc((size_t)E * 4);          // dst-sorted src ids
    float* dinv   = (float*)alloc((size_t)N * 4);
    uint*  hb     = (uint*)alloc((size_t)N * 32 * 4);    // h'  bf16 [N][64]
    float* o1     = (float*)alloc((size_t)N * NHID * 4); // f32 [N][64]
    uint*  h2b    = (uint*)alloc((size_t)N * 12 * 4);    // h2' bf16 [N][24]

    const int B = 256;
    int nb = (N + 1023) / 1024;

    hipMemsetAsync(cnt, 0, (size_t)N * 4, stream);
    k_count  <<<(E + B - 1) / B, B, 0, stream>>>(dst, cnt, E);
    k_scan1  <<<nb, 256, 0, stream>>>(cnt, rowptr, bsum, dinv, N);
    k_scan2  <<<1, 128, 0, stream>>>(bsum, nb);
    k_scan3  <<<nb, 256, 0, stream>>>(rowptr, fill, bfill, bsum, N, E);
    if (N <= (1 << 17)) {
        k_bscatter<<<(E + B - 1) / B, B, 0, stream>>>(src, dst, bfill, ebuf, E);
        k_bsort   <<<NB, 256, 0, stream>>>(rowptr, ebuf, esrc, fill, N);
    } else {
        k_scatter_direct<<<(E + B - 1) / B, B, 0, stream>>>(src, dst, fill, esrc, E);
    }

    k_gemm1  <<<(N + 63) / 64, 256, 0, stream>>>(x, W1, dinv, hb, N);
    k_agg1   <<<(N + 3) / 4, 256, 0, stream>>>(rowptr, esrc, hb, dinv, b1, o1, N);
    k_gemm2  <<<(N + 127) / 128, 128, 0, stream>>>(o1, W2, dinv, h2b, N);
    k_agg2   <<<(N + 63) / 64, 256, 0, stream>>>(rowptr, esrc, h2b, dinv, b2, out, N);
}

// Round 5
// 326.065 us; speedup vs baseline: 1.8822x; 1.8822x over previous
//
#include <hip/hip_runtime.h>

#define NFEAT 128
#define NHID  64
#define NOUT  21
#define BSH   7            // 128 nodes / bucket
#define BCAP  8192         // max edges LDS-sorted per bucket
#define CHUNK 4096         // edges per scatter block
#define NS    8            // stripes (~XCDs)
#define PADI  16           // ints per padded counter (64 B)

typedef unsigned int uint;

// bf16 pack/unpack (RTN-even)
__device__ inline uint packbf2(float a, float b) {
    uint ua = __float_as_uint(a), ub = __float_as_uint(b);
    ua = (ua + 0x7FFFu + ((ua >> 16) & 1u)) >> 16;
    ub = (ub + 0x7FFFu + ((ub >> 16) & 1u)) >> 16;
    return ua | (ub << 16);
}
__device__ inline float bflo(uint v) { return __uint_as_float(v << 16); }
__device__ inline float bfhi(uint v) { return __uint_as_float(v & 0xffff0000u); }

// ================= CSR build =================

__global__ __launch_bounds__(256) void k_count(const int* __restrict__ dst, int* cnt, int E) {
    int e = blockIdx.x * 256 + threadIdx.x;
    if (e < E) atomicAdd(&cnt[dst[e]], 1);
}

__global__ __launch_bounds__(256) void k_scan1(const int* __restrict__ cnt, int* __restrict__ rowptr,
                                               int* __restrict__ bsum, float* __restrict__ dinv, int N) {
    __shared__ int sh[256];
    int tid = threadIdx.x;
    int base = blockIdx.x * 1024 + tid * 4;
    int v[4]; int s = 0;
#pragma unroll
    for (int j = 0; j < 4; ++j) {
        v[j] = (base + j < N) ? cnt[base + j] : 0;
        if (base + j < N) dinv[base + j] = rsqrtf((float)(v[j] + 1));
        s += v[j];
    }
    sh[tid] = s; __syncthreads();
    for (int off = 1; off < 256; off <<= 1) {
        int t = (tid >= off) ? sh[tid - off] : 0;
        __syncthreads();
        sh[tid] += t;
        __syncthreads();
    }
    int run = sh[tid] - s;
#pragma unroll
    for (int j = 0; j < 4; ++j) { if (base + j < N) rowptr[base + j] = run; run += v[j]; }
    if (tid == 255) bsum[blockIdx.x] = sh[255];
}

__global__ __launch_bounds__(128) void k_scan2(int* bsum, int nb) {
    __shared__ int sh[128];
    int tid = threadIdx.x;
    int v = (tid < nb) ? bsum[tid] : 0;
    sh[tid] = v; __syncthreads();
    for (int off = 1; off < 128; off <<= 1) {
        int t = (tid >= off) ? sh[tid - off] : 0;
        __syncthreads();
        sh[tid] += t;
        __syncthreads();
    }
    if (tid < nb) bsum[tid] = sh[tid] - v;
}

__global__ __launch_bounds__(256) void k_scan3(int* __restrict__ rowptr, int* __restrict__ fill,
                                               const int* __restrict__ bsum, int N, int E) {
    int tid = threadIdx.x;
    int base = blockIdx.x * 1024 + tid * 4;
    int add = bsum[blockIdx.x];
#pragma unroll
    for (int j = 0; j < 4; ++j) {
        int idx = base + j;
        if (idx < N) {
            int r = rowptr[idx] + add;
            rowptr[idx] = r;
            fill[idx] = r;
        }
    }
    if (blockIdx.x == 0 && tid == 0) rowptr[N] = E;
}

// per-(bucket,stripe) histogram; stripe = chunk_index & 7 (deterministic)
__global__ __launch_bounds__(256) void k_hist2(const int* __restrict__ dst, int* __restrict__ cnt2,
                                               int E, int nbuk) {
    __shared__ int lh[1024];
    int blk = blockIdx.x, tid = threadIdx.x, s = blk & (NS - 1);
    for (int j = tid; j < nbuk; j += 256) lh[j] = 0;
    __syncthreads();
    int base = blk * CHUNK;
#pragma unroll
    for (int k = 0; k < CHUNK / 256; ++k) {
        int e = base + k * 256 + tid;
        if (e < E) atomicAdd(&lh[dst[e] >> BSH], 1);
    }
    __syncthreads();
    for (int j = tid; j < nbuk; j += 256) {
        int c = lh[j];
        if (c) atomicAdd(&cnt2[(j * NS + s) * PADI], c);
    }
}

// chain stripe segments off rowptr bucket base -> padded cursors cur2
__global__ __launch_bounds__(256) void k_ebase(const int* __restrict__ rowptr, const int* __restrict__ cnt2,
                                               int* __restrict__ cur2, int nbuk) {
    int b = blockIdx.x * 256 + threadIdx.x;
    if (b >= nbuk) return;
    int base = rowptr[b << BSH];
#pragma unroll
    for (int s = 0; s < NS; ++s) {
        cur2[(b * NS + s) * PADI] = base;
        base += cnt2[(b * NS + s) * PADI];
    }
}

// striped bucket scatter: padded per-(bucket,stripe) cursors
__global__ __launch_bounds__(256) void k_bscatter2(const int* __restrict__ src, const int* __restrict__ dst,
                                                   int* __restrict__ cur2, uint* __restrict__ ebuf, int E) {
    int blk = blockIdx.x, tid = threadIdx.x, s = blk & (NS - 1);
    int base = blk * CHUNK;
#pragma unroll
    for (int k = 0; k < CHUNK / 256; ++k) {
        int e = base + k * 256 + tid;
        if (e >= E) return;
        int d = dst[e];
        int pos = atomicAdd(&cur2[((d >> BSH) * NS + s) * PADI], 1);
        ebuf[pos] = ((uint)(d & ((1 << BSH) - 1)) << 17) | (uint)src[e];
    }
}

// per-bucket LDS counting sort -> esrc, coalesced output
__global__ __launch_bounds__(256) void k_bsort(const int* __restrict__ rowptr, const uint* __restrict__ ebuf,
                                               int* __restrict__ esrc, int* __restrict__ fill, int N) {
    __shared__ int  lcur[1 << BSH];
    __shared__ int  lsort[BCAP];
    int b = blockIdx.x;
    int tid = threadIdx.x;
    int nb0 = b << BSH;
    int nend = min(nb0 + (1 << BSH), N);
    int bbase = rowptr[nb0];
    int bend  = rowptr[nend];
    int cnt_b = bend - bbase;
    if (cnt_b <= 0) return;
    if (cnt_b <= BCAP) {
        if (tid < (1 << BSH)) {
            int node = nb0 + tid;
            lcur[tid] = (node < N ? rowptr[node] : bend) - bbase;
        }
        __syncthreads();
        for (int i = tid; i < cnt_b; i += 256) {
            uint v = ebuf[bbase + i];
            int pos = atomicAdd(&lcur[v >> 17], 1);
            lsort[pos] = (int)(v & 0x1FFFFu);
        }
        __syncthreads();
        for (int i = tid; i < cnt_b; i += 256) esrc[bbase + i] = lsort[i];
    } else {
        for (int i = tid; i < cnt_b; i += 256) {
            uint v = ebuf[bbase + i];
            int pos = atomicAdd(&fill[nb0 + (int)(v >> 17)], 1);
            esrc[pos] = (int)(v & 0x1FFFFu);
        }
    }
}

// general-N fallback: direct scatter with per-node cursors
__global__ __launch_bounds__(256) void k_scatter_direct(const int* __restrict__ src, const int* __restrict__ dst,
                                                        int* __restrict__ fill, int* __restrict__ esrc, int E) {
    int e = blockIdx.x * 256 + threadIdx.x;
    if (e >= E) return;
    int pos = atomicAdd(&fill[dst[e]], 1);
    esrc[pos] = src[e];
}

// ===== GEMM1: h' = dinv * (x @ W1), stored packed bf16 [N][32 uints] =====

__global__ __launch_bounds__(256) void k_gemm1(const float* __restrict__ x, const float* __restrict__ W1,
                                               const float* __restrict__ dinv, uint* __restrict__ hb, int N) {
    __shared__ float Ws[NFEAT * NHID];  // 32 KB
    int tid = threadIdx.x;
#pragma unroll
    for (int i = 0; i < 8; ++i) {
        int idx = (tid + i * 256) * 4;
        *(float4*)&Ws[idx] = *(const float4*)&W1[idx];
    }
    __syncthreads();
    int row = blockIdx.x * 64 + (tid >> 2);
    if (row >= N) return;
    int cg = (tid & 3) * 16;
    float acc[16];
#pragma unroll
    for (int j = 0; j < 16; ++j) acc[j] = 0.f;
    const float* xr = x + (size_t)row * NFEAT;
#pragma unroll 4
    for (int k4 = 0; k4 < NFEAT / 4; ++k4) {
        float4 xv = *(const float4*)&xr[k4 * 4];
        float xs[4] = {xv.x, xv.y, xv.z, xv.w};
#pragma unroll
        for (int kk = 0; kk < 4; ++kk) {
            const float* wrow = &Ws[(k4 * 4 + kk) * NHID + cg];
#pragma unroll
            for (int j4 = 0; j4 < 4; ++j4) {
                float4 w = *(const float4*)&wrow[j4 * 4];
                acc[j4 * 4 + 0] = fmaf(xs[kk], w.x, acc[j4 * 4 + 0]);
                acc[j4 * 4 + 1] = fmaf(xs[kk], w.y, acc[j4 * 4 + 1]);
                acc[j4 * 4 + 2] = fmaf(xs[kk], w.z, acc[j4 * 4 + 2]);
                acc[j4 * 4 + 3] = fmaf(xs[kk], w.w, acc[j4 * 4 + 3]);
            }
        }
    }
    float dv = dinv[row];
    uint up[8];
#pragma unroll
    for (int j = 0; j < 8; ++j) up[j] = packbf2(acc[2 * j] * dv, acc[2 * j + 1] * dv);
    uint* hr = hb + (size_t)row * 32 + (tid & 3) * 8;
    ((uint4*)hr)[0] = make_uint4(up[0], up[1], up[2], up[3]);
    ((uint4*)hr)[1] = make_uint4(up[4], up[5], up[6], up[7]);
}

// ===== agg1: o1[d] = relu(b1 + dv_d*(h'[d] + sum_e h'[src_e])) =====

__global__ __launch_bounds__(256) void k_agg1(const int* __restrict__ rowptr, const int* __restrict__ esrc,
                                              const uint* __restrict__ hb, const float* __restrict__ dinv,
                                              const float* __restrict__ b1, float* __restrict__ o1, int N) {
    int tid = threadIdx.x;
    int node = blockIdx.x * 4 + (tid >> 6);
    if (node >= N) return;
    int lane = tid & 63;
    int half = lane >> 5;
    int c = lane & 31;
    uint sv = hb[(size_t)node * 32 + c];
    float ax = half ? 0.f : bflo(sv);
    float ay = half ? 0.f : bfhi(sv);
    int beg = rowptr[node], end = rowptr[node + 1];
    int i = beg + half;
    for (; i + 2 < end; i += 4) {
        int s0 = esrc[i], s1 = esrc[i + 2];
        uint v0 = hb[(size_t)s0 * 32 + c];
        uint v1 = hb[(size_t)s1 * 32 + c];
        ax += bflo(v0); ay += bfhi(v0);
        ax += bflo(v1); ay += bfhi(v1);
    }
    if (i < end) {
        uint v = hb[(size_t)esrc[i] * 32 + c];
        ax += bflo(v); ay += bfhi(v);
    }
    ax += __shfl_xor(ax, 32);
    ay += __shfl_xor(ay, 32);
    if (!half) {
        float dv = dinv[node];
        float2 bv = ((const float2*)b1)[c];
        float2 r;
        r.x = fmaxf(fmaf(ax, dv, bv.x), 0.f);
        r.y = fmaxf(fmaf(ay, dv, bv.y), 0.f);
        ((float2*)(o1 + (size_t)node * NHID))[c] = r;
    }
}

// ===== GEMM2: h2' = dinv * (o1 @ W2), packed bf16 padded to 24 feats =====

__global__ __launch_bounds__(128) void k_gemm2(const float* __restrict__ o1, const float* __restrict__ W2,
                                               const float* __restrict__ dinv, uint* __restrict__ h2b, int N) {
    __shared__ float rs[128 * 65];
    __shared__ float Ws[NHID * NOUT];
    int tid = threadIdx.x;
    for (int i = tid; i < NHID * NOUT; i += 128) Ws[i] = W2[i];
    int base = blockIdx.x * 128;
#pragma unroll
    for (int i = 0; i < 16; ++i) {
        int idx = tid + i * 128;
        int row = idx >> 4;
        int f4 = (idx & 15) * 4;
        int grow = base + row;
        float4 v = make_float4(0.f, 0.f, 0.f, 0.f);
        if (grow < N) v = *(const float4*)&o1[(size_t)grow * NHID + f4];
        float* d = &rs[row * 65 + f4];
        d[0] = v.x; d[1] = v.y; d[2] = v.z; d[3] = v.w;
    }
    __syncthreads();
    int row = base + tid;
    if (row >= N) return;
    float acc[NOUT];
#pragma unroll
    for (int j = 0; j < NOUT; ++j) acc[j] = 0.f;
    for (int k = 0; k < NHID; ++k) {
        float av = rs[tid * 65 + k];
#pragma unroll
        for (int j = 0; j < NOUT; ++j) acc[j] = fmaf(av, Ws[k * NOUT + j], acc[j]);
    }
    float dv = dinv[row];
    uint up[12];
#pragma unroll
    for (int j = 0; j < 10; ++j) up[j] = packbf2(acc[2 * j] * dv, acc[2 * j + 1] * dv);
    up[10] = packbf2(acc[20] * dv, 0.f);
    up[11] = 0u;
    uint* hr = h2b + (size_t)row * 12;
    ((uint4*)hr)[0] = make_uint4(up[0], up[1], up[2], up[3]);
    ((uint4*)hr)[1] = make_uint4(up[4], up[5], up[6], up[7]);
    ((uint4*)hr)[2] = make_uint4(up[8], up[9], up[10], up[11]);
}

// ===== agg2: out[d] = b2 + dv_d*(h2'[d] + sum_e h2'[src_e]) =====

__global__ __launch_bounds__(256) void k_agg2(const int* __restrict__ rowptr, const int* __restrict__ esrc,
                                              const uint* __restrict__ h2b, const float* __restrict__ dinv,
                                              const float* __restrict__ b2, float* __restrict__ out, int N) {
    int tid = threadIdx.x;
    int node = blockIdx.x * 64 + (tid >> 2);
    if (node >= N) return;
    int q = tid & 3;
    const uint* sp = h2b + (size_t)node * 12 + q * 3;
    uint u0 = sp[0], u1 = sp[1], u2 = sp[2];
    float a0 = bflo(u0), a1 = bfhi(u0), a2 = bflo(u1), a3 = bfhi(u1), a4 = bflo(u2), a5 = bfhi(u2);
    int beg = rowptr[node], end = rowptr[node + 1];
    int i = beg;
    for (; i + 1 < end; i += 2) {
        const uint* p0 = h2b + (size_t)esrc[i] * 12 + q * 3;
        const uint* p1 = h2b + (size_t)esrc[i + 1] * 12 + q * 3;
        uint x0 = p0[0], x1 = p0[1], x2 = p0[2];
        uint y0 = p1[0], y1 = p1[1], y2 = p1[2];
        a0 += bflo(x0) + bflo(y0); a1 += bfhi(x0) + bfhi(y0);
        a2 += bflo(x1) + bflo(y1); a3 += bfhi(x1) + bfhi(y1);
        a4 += bflo(x2) + bflo(y2); a5 += bfhi(x2) + bfhi(y2);
    }
    if (i < end) {
        const uint* p0 = h2b + (size_t)esrc[i] * 12 + q * 3;
        uint x0 = p0[0], x1 = p0[1], x2 = p0[2];
        a0 += bflo(x0); a1 += bfhi(x0);
        a2 += bflo(x1); a3 += bfhi(x1);
        a4 += bflo(x2); a5 += bfhi(x2);
    }
    float dv = dinv[node];
    float* orow = out + (size_t)node * NOUT;
    int col = q * 6;
    float av[6] = {a0, a1, a2, a3, a4, a5};
#pragma unroll
    for (int j = 0; j < 6; ++j)
        if (col + j < NOUT) orow[col + j] = fmaf(dv, av[j], b2[col + j]);
}

// ================= launch =================

extern "C" void kernel_launch(void* const* d_in, const int* in_sizes, int n_in,
                              void* d_out, int out_size, void* d_ws, size_t ws_size,
                              hipStream_t stream) {
    const float* x  = (const float*)d_in[0];
    const int*   ei = (const int*)d_in[1];
    const float* W1 = (const float*)d_in[2];
    const float* b1 = (const float*)d_in[3];
    const float* W2 = (const float*)d_in[4];
    const float* b2 = (const float*)d_in[5];
    float* out = (float*)d_out;

    int N = in_sizes[0] / NFEAT;
    int E = in_sizes[1] / 2;
    const int* src = ei;
    const int* dst = ei + E;
    int NBUK = (N + (1 << BSH) - 1) >> BSH;
    int NCHUNK = (E + CHUNK - 1) / CHUNK;

    char* p = (char*)d_ws;
    auto alloc = [&](size_t bytes) { void* r = (void*)p; p += (bytes + 255) & ~(size_t)255; return r; };
    int*   cnt    = (int*)alloc((size_t)N * 4);
    int*   rowptr = (int*)alloc((size_t)(N + 1) * 4);
    int*   fill   = (int*)alloc((size_t)N * 4);
    int*   bsum   = (int*)alloc(128 * 4);
    int*   cnt2   = (int*)alloc((size_t)NBUK * NS * PADI * 4);   // padded counts
    int*   cur2   = (int*)alloc((size_t)NBUK * NS * PADI * 4);   // padded cursors
    uint*  ebuf   = (uint*)alloc((size_t)E * 4);
    int*   esrc   = (int*)alloc((size_t)E * 4);
    float* dinv   = (float*)alloc((size_t)N * 4);
    uint*  hb     = (uint*)alloc((size_t)N * 32 * 4);
    float* o1     = (float*)alloc((size_t)N * NHID * 4);
    uint*  h2b    = (uint*)alloc((size_t)N * 12 * 4);

    const int B = 256;
    int nb = (N + 1023) / 1024;

    hipMemsetAsync(cnt, 0, (size_t)N * 4, stream);
    hipMemsetAsync(cnt2, 0, (size_t)NBUK * NS * PADI * 4, stream);
    k_count  <<<(E + B - 1) / B, B, 0, stream>>>(dst, cnt, E);
    k_scan1  <<<nb, 256, 0, stream>>>(cnt, rowptr, bsum, dinv, N);
    k_scan2  <<<1, 128, 0, stream>>>(bsum, nb);
    k_scan3  <<<nb, 256, 0, stream>>>(rowptr, fill, bsum, N, E);
    if (N <= (1 << 17)) {
        k_hist2    <<<NCHUNK, 256, 0, stream>>>(dst, cnt2, E, NBUK);
        k_ebase    <<<(NBUK + 255) / 256, 256, 0, stream>>>(rowptr, cnt2, cur2, NBUK);
        k_bscatter2<<<NCHUNK, 256, 0, stream>>>(src, dst, cur2, ebuf, E);
        k_bsort    <<<NBUK, 256, 0, stream>>>(rowptr, ebuf, esrc, fill, N);
    } else {
        k_scatter_direct<<<(E + B - 1) / B, B, 0, stream>>>(src, dst, fill, esrc, E);
    }

    k_gemm1  <<<(N + 63) / 64, 256, 0, stream>>>(x, W1, dinv, hb, N);
    k_agg1   <<<(N + 3) / 4, 256, 0, stream>>>(rowptr, esrc, hb, dinv, b1, o1, N);
    k_gemm2  <<<(N + 127) / 128, 128, 0, stream>>>(o1, W2, dinv, h2b, N);
    k_agg2   <<<(N + 63) / 64, 256, 0, stream>>>(rowptr, esrc, h2b, dinv, b2, out, N);
}

// Round 6
// 213.113 us; speedup vs baseline: 2.8797x; 1.5300x over previous
//
#include <hip/hip_runtime.h>

#define NFEAT 128
#define NHID  64
#define NOUT  21
#define BSH   7            // 128 nodes / bucket
#define BCAP  8192         // max edges LDS-sorted per bucket
#define CHUNK 4096         // edges per sort block (16 KB private region)
#define EPT   (CHUNK/256)  // edges per thread in k_lsort
#define PADI  16           // ints per padded counter (64 B)
#define NBUKMAX 1024       // nbuk ceiling for the packed path (N <= 2^17)

typedef unsigned int uint;

// bf16 pack/unpack (RTN-even)
__device__ inline uint packbf2(float a, float b) {
    uint ua = __float_as_uint(a), ub = __float_as_uint(b);
    ua = (ua + 0x7FFFu + ((ua >> 16) & 1u)) >> 16;
    ub = (ub + 0x7FFFu + ((ub >> 16) & 1u)) >> 16;
    return ua | (ub << 16);
}
__device__ inline float bflo(uint v) { return __uint_as_float(v << 16); }
__device__ inline float bfhi(uint v) { return __uint_as_float(v & 0xffff0000u); }

// ============ pass A: per-chunk LDS counting sort by bucket ============
// Each block owns a private contiguous ebuf region -> every HBM line is
// written by exactly one block (no cross-XCD partial-line sharing).

__global__ __launch_bounds__(256) void k_lsort(const int* __restrict__ src, const int* __restrict__ dst,
                                               uint* __restrict__ ebuf, int* __restrict__ tab,
                                               int* __restrict__ gcnt, int E, int nbuk) {
    __shared__ int  lcnt[NBUKMAX + 1];
    __shared__ int  lsum[256];
    __shared__ uint lsorted[CHUNK];
    int c = blockIdx.x, tid = threadIdx.x;
    int base = c * CHUNK;
    int ccnt = min(CHUNK, E - base);

    for (int j = tid; j <= nbuk; j += 256) lcnt[j] = 0;
    __syncthreads();

    int  buk[EPT];
    uint rec[EPT];
#pragma unroll
    for (int k = 0; k < EPT; ++k) {
        int e = base + k * 256 + tid;
        if (e < E) {
            int d = dst[e];
            buk[k] = d >> BSH;
            rec[k] = ((uint)(d & ((1 << BSH) - 1)) << 17) | (uint)src[e];
            atomicAdd(&lcnt[buk[k]], 1);
        }
    }
    __syncthreads();

    // exclusive scan of lcnt[0..nbuk): per-thread serial over g owned entries + block scan
    int g = (nbuk + 255) / 256;
    int j0 = tid * g;
    int s = 0;
    for (int j = 0; j < g; ++j) { int idx = j0 + j; if (idx < nbuk) s += lcnt[idx]; }
    lsum[tid] = s;
    __syncthreads();
    for (int off = 1; off < 256; off <<= 1) {
        int t = (tid >= off) ? lsum[tid - off] : 0;
        __syncthreads();
        lsum[tid] += t;
        __syncthreads();
    }
    int run = lsum[tid] - s;
    for (int j = 0; j < g; ++j) {           // in-place rewrite to exclusive offsets (disjoint ownership)
        int idx = j0 + j;
        if (idx < nbuk) { int cv = lcnt[idx]; lcnt[idx] = run; run += cv; }
    }
    __syncthreads();
    if (tid == 0) lcnt[nbuk] = ccnt;
    __syncthreads();

    // emit table row + per-bucket global totals (reads lcnt before cursor mutation)
    for (int j = tid; j < nbuk; j += 256) {
        int st = lcnt[j];
        tab[(size_t)c * (nbuk + 1) + j] = st;
        int cj = lcnt[j + 1] - st;
        if (cj) atomicAdd(&gcnt[j * PADI], cj);
    }
    if (tid == 0) tab[(size_t)c * (nbuk + 1) + nbuk] = ccnt;
    __syncthreads();

    // place into LDS sorted order (lcnt now cursors), flush coalesced
#pragma unroll
    for (int k = 0; k < EPT; ++k) {
        int e = base + k * 256 + tid;
        if (e < E) {
            int pos = atomicAdd(&lcnt[buk[k]], 1);
            lsorted[pos] = rec[k];
        }
    }
    __syncthreads();
    for (int i = tid; i < ccnt; i += 256) ebuf[base + i] = lsorted[i];
}

// ============ scan bucket totals -> bucket bases ============

__global__ __launch_bounds__(256) void k_bscan(const int* __restrict__ gcnt, int* __restrict__ bbase,
                                               int* __restrict__ rowptr, int nbuk, int N, int E) {
    __shared__ int lv[NBUKMAX];
    __shared__ int lsum[256];
    int tid = threadIdx.x;
    int g = (nbuk + 255) / 256;
    int j0 = tid * g;
    int s = 0;
    for (int j = 0; j < g; ++j) {
        int idx = j0 + j;
        int v = (idx < nbuk) ? gcnt[idx * PADI] : 0;
        if (idx < nbuk) lv[idx] = v;
        s += v;
    }
    lsum[tid] = s;
    __syncthreads();
    for (int off = 1; off < 256; off <<= 1) {
        int t = (tid >= off) ? lsum[tid - off] : 0;
        __syncthreads();
        lsum[tid] += t;
        __syncthreads();
    }
    int run = lsum[tid] - s;
    for (int j = 0; j < g; ++j) {
        int idx = j0 + j;
        if (idx < nbuk) { bbase[idx] = run; run += lv[idx]; }
    }
    if (tid == 0) rowptr[N] = E;
}

// ============ pass B: per-bucket gather + node sort; emits rowptr/dinv/esrc ============

__global__ __launch_bounds__(256) void k_bsort2(const uint* __restrict__ ebuf, const int* __restrict__ tab,
                                                const int* __restrict__ bbase_, const int* __restrict__ gcnt,
                                                int* __restrict__ rowptr, float* __restrict__ dinv,
                                                int* __restrict__ esrc, int nchunk, int nbuk, int N) {
    __shared__ int ncnt[128];
    __shared__ int sc[128];
    __shared__ int lcur[128];
    __shared__ int lsort[BCAP];
    int b = blockIdx.x, tid = threadIdx.x;
    int nb0 = b << BSH;
    int bb = bbase_[b];
    int cnt_b = gcnt[b * PADI];

    if (tid < 128) ncnt[tid] = 0;
    __syncthreads();

    // phase 1: count records per node
    for (int c = tid; c < nchunk; c += 256) {
        const int* trow = tab + (size_t)c * (nbuk + 1);
        int s0 = trow[b], e0 = trow[b + 1];
        const uint* pb = ebuf + (size_t)c * CHUNK;
        for (int i = s0; i < e0; ++i) atomicAdd(&ncnt[pb[i] >> 17], 1);
    }
    __syncthreads();

    // exclusive scan over 128 node counts
    int v = (tid < 128) ? ncnt[tid] : 0;
    if (tid < 128) sc[tid] = v;
    __syncthreads();
    for (int off = 1; off < 128; off <<= 1) {
        int t = (tid >= off && tid < 128) ? sc[tid - off] : 0;
        __syncthreads();
        if (tid < 128) sc[tid] += t;
        __syncthreads();
    }
    if (tid < 128) {
        int excl = sc[tid] - v;
        int node = nb0 + tid;
        if (node < N) {
            rowptr[node] = bb + excl;
            dinv[node] = rsqrtf((float)(v + 1));   // in-degree + self-loop
        }
        lcur[tid] = (cnt_b <= BCAP) ? excl : (bb + excl);
    }
    __syncthreads();

    // phase 2: place by node, flush coalesced
    if (cnt_b <= BCAP) {
        for (int c = tid; c < nchunk; c += 256) {
            const int* trow = tab + (size_t)c * (nbuk + 1);
            int s0 = trow[b], e0 = trow[b + 1];
            const uint* pb = ebuf + (size_t)c * CHUNK;
            for (int i = s0; i < e0; ++i) {
                uint r = pb[i];
                int pos = atomicAdd(&lcur[r >> 17], 1);
                lsort[pos] = (int)(r & 0x1FFFFu);
            }
        }
        __syncthreads();
        for (int i = tid; i < cnt_b; i += 256) esrc[bb + i] = lsort[i];
    } else {
        // oversized bucket: direct global placement (absolute cursors)
        for (int c = tid; c < nchunk; c += 256) {
            const int* trow = tab + (size_t)c * (nbuk + 1);
            int s0 = trow[b], e0 = trow[b + 1];
            const uint* pb = ebuf + (size_t)c * CHUNK;
            for (int i = s0; i < e0; ++i) {
                uint r = pb[i];
                int pos = atomicAdd(&lcur[r >> 17], 1);
                esrc[pos] = (int)(r & 0x1FFFFu);
            }
        }
    }
}

// ============ general-N fallback (N > 2^17): naive CSR build ============

__global__ __launch_bounds__(256) void k_count(const int* __restrict__ dst, int* cnt, int E) {
    int e = blockIdx.x * 256 + threadIdx.x;
    if (e < E) atomicAdd(&cnt[dst[e]], 1);
}

__global__ __launch_bounds__(256) void k_scan1(const int* __restrict__ cnt, int* __restrict__ rowptr,
                                               int* __restrict__ bsum, float* __restrict__ dinv, int N) {
    __shared__ int sh[256];
    int tid = threadIdx.x;
    int base = blockIdx.x * 1024 + tid * 4;
    int v[4]; int s = 0;
#pragma unroll
    for (int j = 0; j < 4; ++j) {
        v[j] = (base + j < N) ? cnt[base + j] : 0;
        if (base + j < N) dinv[base + j] = rsqrtf((float)(v[j] + 1));
        s += v[j];
    }
    sh[tid] = s; __syncthreads();
    for (int off = 1; off < 256; off <<= 1) {
        int t = (tid >= off) ? sh[tid - off] : 0;
        __syncthreads();
        sh[tid] += t;
        __syncthreads();
    }
    int run = sh[tid] - s;
#pragma unroll
    for (int j = 0; j < 4; ++j) { if (base + j < N) rowptr[base + j] = run; run += v[j]; }
    if (tid == 255) bsum[blockIdx.x] = sh[255];
}

__global__ __launch_bounds__(128) void k_scan2(int* bsum, int nb) {
    __shared__ int sh[128];
    int tid = threadIdx.x;
    int v = (tid < nb) ? bsum[tid] : 0;
    sh[tid] = v; __syncthreads();
    for (int off = 1; off < 128; off <<= 1) {
        int t = (tid >= off) ? sh[tid - off] : 0;
        __syncthreads();
        sh[tid] += t;
        __syncthreads();
    }
    if (tid < nb) bsum[tid] = sh[tid] - v;
}

__global__ __launch_bounds__(256) void k_scan3(int* __restrict__ rowptr, int* __restrict__ fill,
                                               const int* __restrict__ bsum, int N, int E) {
    int tid = threadIdx.x;
    int base = blockIdx.x * 1024 + tid * 4;
    int add = bsum[blockIdx.x];
#pragma unroll
    for (int j = 0; j < 4; ++j) {
        int idx = base + j;
        if (idx < N) {
            int r = rowptr[idx] + add;
            rowptr[idx] = r;
            fill[idx] = r;
        }
    }
    if (blockIdx.x == 0 && tid == 0) rowptr[N] = E;
}

__global__ __launch_bounds__(256) void k_scatter_direct(const int* __restrict__ src, const int* __restrict__ dst,
                                                        int* __restrict__ fill, int* __restrict__ esrc, int E) {
    int e = blockIdx.x * 256 + threadIdx.x;
    if (e >= E) return;
    int pos = atomicAdd(&fill[dst[e]], 1);
    esrc[pos] = src[e];
}

// ===== GEMM1: h' = dinv * (x @ W1), stored packed bf16 [N][32 uints] =====

__global__ __launch_bounds__(256) void k_gemm1(const float* __restrict__ x, const float* __restrict__ W1,
                                               const float* __restrict__ dinv, uint* __restrict__ hb, int N) {
    __shared__ float Ws[NFEAT * NHID];  // 32 KB
    int tid = threadIdx.x;
#pragma unroll
    for (int i = 0; i < 8; ++i) {
        int idx = (tid + i * 256) * 4;
        *(float4*)&Ws[idx] = *(const float4*)&W1[idx];
    }
    __syncthreads();
    int row = blockIdx.x * 64 + (tid >> 2);
    if (row >= N) return;
    int cg = (tid & 3) * 16;
    float acc[16];
#pragma unroll
    for (int j = 0; j < 16; ++j) acc[j] = 0.f;
    const float* xr = x + (size_t)row * NFEAT;
#pragma unroll 4
    for (int k4 = 0; k4 < NFEAT / 4; ++k4) {
        float4 xv = *(const float4*)&xr[k4 * 4];
        float xs[4] = {xv.x, xv.y, xv.z, xv.w};
#pragma unroll
        for (int kk = 0; kk < 4; ++kk) {
            const float* wrow = &Ws[(k4 * 4 + kk) * NHID + cg];
#pragma unroll
            for (int j4 = 0; j4 < 4; ++j4) {
                float4 w = *(const float4*)&wrow[j4 * 4];
                acc[j4 * 4 + 0] = fmaf(xs[kk], w.x, acc[j4 * 4 + 0]);
                acc[j4 * 4 + 1] = fmaf(xs[kk], w.y, acc[j4 * 4 + 1]);
                acc[j4 * 4 + 2] = fmaf(xs[kk], w.z, acc[j4 * 4 + 2]);
                acc[j4 * 4 + 3] = fmaf(xs[kk], w.w, acc[j4 * 4 + 3]);
            }
        }
    }
    float dv = dinv[row];
    uint up[8];
#pragma unroll
    for (int j = 0; j < 8; ++j) up[j] = packbf2(acc[2 * j] * dv, acc[2 * j + 1] * dv);
    uint* hr = hb + (size_t)row * 32 + (tid & 3) * 8;
    ((uint4*)hr)[0] = make_uint4(up[0], up[1], up[2], up[3]);
    ((uint4*)hr)[1] = make_uint4(up[4], up[5], up[6], up[7]);
}

// ===== agg1: o1[d] = relu(b1 + dv_d*(h'[d] + sum_e h'[src_e])) =====

__global__ __launch_bounds__(256) void k_agg1(const int* __restrict__ rowptr, const int* __restrict__ esrc,
                                              const uint* __restrict__ hb, const float* __restrict__ dinv,
                                              const float* __restrict__ b1, float* __restrict__ o1, int N) {
    int tid = threadIdx.x;
    int node = blockIdx.x * 4 + (tid >> 6);
    if (node >= N) return;
    int lane = tid & 63;
    int half = lane >> 5;
    int c = lane & 31;
    uint sv = hb[(size_t)node * 32 + c];
    float ax = half ? 0.f : bflo(sv);
    float ay = half ? 0.f : bfhi(sv);
    int beg = rowptr[node], end = rowptr[node + 1];
    int i = beg + half;
    for (; i + 2 < end; i += 4) {
        int s0 = esrc[i], s1 = esrc[i + 2];
        uint v0 = hb[(size_t)s0 * 32 + c];
        uint v1 = hb[(size_t)s1 * 32 + c];
        ax += bflo(v0); ay += bfhi(v0);
        ax += bflo(v1); ay += bfhi(v1);
    }
    if (i < end) {
        uint v = hb[(size_t)esrc[i] * 32 + c];
        ax += bflo(v); ay += bfhi(v);
    }
    ax += __shfl_xor(ax, 32);
    ay += __shfl_xor(ay, 32);
    if (!half) {
        float dv = dinv[node];
        float2 bv = ((const float2*)b1)[c];
        float2 r;
        r.x = fmaxf(fmaf(ax, dv, bv.x), 0.f);
        r.y = fmaxf(fmaf(ay, dv, bv.y), 0.f);
        ((float2*)(o1 + (size_t)node * NHID))[c] = r;
    }
}

// ===== GEMM2: h2' = dinv * (o1 @ W2), packed bf16 padded to 24 feats =====

__global__ __launch_bounds__(128) void k_gemm2(const float* __restrict__ o1, const float* __restrict__ W2,
                                               const float* __restrict__ dinv, uint* __restrict__ h2b, int N) {
    __shared__ float rs[128 * 65];
    __shared__ float Ws[NHID * NOUT];
    int tid = threadIdx.x;
    for (int i = tid; i < NHID * NOUT; i += 128) Ws[i] = W2[i];
    int base = blockIdx.x * 128;
#pragma unroll
    for (int i = 0; i < 16; ++i) {
        int idx = tid + i * 128;
        int row = idx >> 4;
        int f4 = (idx & 15) * 4;
        int grow = base + row;
        float4 v = make_float4(0.f, 0.f, 0.f, 0.f);
        if (grow < N) v = *(const float4*)&o1[(size_t)grow * NHID + f4];
        float* d = &rs[row * 65 + f4];
        d[0] = v.x; d[1] = v.y; d[2] = v.z; d[3] = v.w;
    }
    __syncthreads();
    int row = base + tid;
    if (row >= N) return;
    float acc[NOUT];
#pragma unroll
    for (int j = 0; j < NOUT; ++j) acc[j] = 0.f;
    for (int k = 0; k < NHID; ++k) {
        float av = rs[tid * 65 + k];
#pragma unroll
        for (int j = 0; j < NOUT; ++j) acc[j] = fmaf(av, Ws[k * NOUT + j], acc[j]);
    }
    float dv = dinv[row];
    uint up[12];
#pragma unroll
    for (int j = 0; j < 10; ++j) up[j] = packbf2(acc[2 * j] * dv, acc[2 * j + 1] * dv);
    up[10] = packbf2(acc[20] * dv, 0.f);
    up[11] = 0u;
    uint* hr = h2b + (size_t)row * 12;
    ((uint4*)hr)[0] = make_uint4(up[0], up[1], up[2], up[3]);
    ((uint4*)hr)[1] = make_uint4(up[4], up[5], up[6], up[7]);
    ((uint4*)hr)[2] = make_uint4(up[8], up[9], up[10], up[11]);
}

// ===== agg2: out[d] = b2 + dv_d*(h2'[d] + sum_e h2'[src_e]) =====

__global__ __launch_bounds__(256) void k_agg2(const int* __restrict__ rowptr, const int* __restrict__ esrc,
                                              const uint* __restrict__ h2b, const float* __restrict__ dinv,
                                              const float* __restrict__ b2, float* __restrict__ out, int N) {
    int tid = threadIdx.x;
    int node = blockIdx.x * 64 + (tid >> 2);
    if (node >= N) return;
    int q = tid & 3;
    const uint* sp = h2b + (size_t)node * 12 + q * 3;
    uint u0 = sp[0], u1 = sp[1], u2 = sp[2];
    float a0 = bflo(u0), a1 = bfhi(u0), a2 = bflo(u1), a3 = bfhi(u1), a4 = bflo(u2), a5 = bfhi(u2);
    int beg = rowptr[node], end = rowptr[node + 1];
    int i = beg;
    for (; i + 1 < end; i += 2) {
        const uint* p0 = h2b + (size_t)esrc[i] * 12 + q * 3;
        const uint* p1 = h2b + (size_t)esrc[i + 1] * 12 + q * 3;
        uint x0 = p0[0], x1 = p0[1], x2 = p0[2];
        uint y0 = p1[0], y1 = p1[1], y2 = p1[2];
        a0 += bflo(x0) + bflo(y0); a1 += bfhi(x0) + bfhi(y0);
        a2 += bflo(x1) + bflo(y1); a3 += bfhi(x1) + bfhi(y1);
        a4 += bflo(x2) + bflo(y2); a5 += bfhi(x2) + bfhi(y2);
    }
    if (i < end) {
        const uint* p0 = h2b + (size_t)esrc[i] * 12 + q * 3;
        uint x0 = p0[0], x1 = p0[1], x2 = p0[2];
        a0 += bflo(x0); a1 += bfhi(x0);
        a2 += bflo(x1); a3 += bfhi(x1);
        a4 += bflo(x2); a5 += bfhi(x2);
    }
    float dv = dinv[node];
    float* orow = out + (size_t)node * NOUT;
    int col = q * 6;
    float av[6] = {a0, a1, a2, a3, a4, a5};
#pragma unroll
    for (int j = 0; j < 6; ++j)
        if (col + j < NOUT) orow[col + j] = fmaf(dv, av[j], b2[col + j]);
}

// ================= launch =================

extern "C" void kernel_launch(void* const* d_in, const int* in_sizes, int n_in,
                              void* d_out, int out_size, void* d_ws, size_t ws_size,
                              hipStream_t stream) {
    const float* x  = (const float*)d_in[0];
    const int*   ei = (const int*)d_in[1];
    const float* W1 = (const float*)d_in[2];
    const float* b1 = (const float*)d_in[3];
    const float* W2 = (const float*)d_in[4];
    const float* b2 = (const float*)d_in[5];
    float* out = (float*)d_out;

    int N = in_sizes[0] / NFEAT;
    int E = in_sizes[1] / 2;
    const int* src = ei;
    const int* dst = ei + E;
    int NBUK = (N + (1 << BSH) - 1) >> BSH;
    int NCHUNK = (E + CHUNK - 1) / CHUNK;

    char* p = (char*)d_ws;
    auto alloc = [&](size_t bytes) { void* r = (void*)p; p += (bytes + 255) & ~(size_t)255; return r; };
    int*   rowptr = (int*)alloc((size_t)(N + 1) * 4);
    int*   gcnt   = (int*)alloc((size_t)NBUK * PADI * 4);
    int*   bbase  = (int*)alloc((size_t)NBUK * 4);
    int*   tab    = (int*)alloc((size_t)NCHUNK * (NBUK + 1) * 4);
    uint*  ebuf   = (uint*)alloc((size_t)E * 4);
    int*   esrc   = (int*)alloc((size_t)E * 4);
    float* dinv   = (float*)alloc((size_t)N * 4);
    uint*  hb     = (uint*)alloc((size_t)N * 32 * 4);
    float* o1     = (float*)alloc((size_t)N * NHID * 4);
    uint*  h2b    = (uint*)alloc((size_t)N * 12 * 4);
    int*   cnt    = (int*)alloc((size_t)N * 4);      // fallback only
    int*   fill   = (int*)alloc((size_t)N * 4);      // fallback only
    int*   bsum   = (int*)alloc(128 * 4);            // fallback only

    const int B = 256;

    if (N <= (1 << 17)) {
        hipMemsetAsync(gcnt, 0, (size_t)NBUK * PADI * 4, stream);
        k_lsort <<<NCHUNK, 256, 0, stream>>>(src, dst, ebuf, tab, gcnt, E, NBUK);
        k_bscan <<<1, 256, 0, stream>>>(gcnt, bbase, rowptr, NBUK, N, E);
        k_bsort2<<<NBUK, 256, 0, stream>>>(ebuf, tab, bbase, gcnt, rowptr, dinv, esrc, NCHUNK, NBUK, N);
    } else {
        int nb = (N + 1023) / 1024;
        hipMemsetAsync(cnt, 0, (size_t)N * 4, stream);
        k_count <<<(E + B - 1) / B, B, 0, stream>>>(dst, cnt, E);
        k_scan1 <<<nb, 256, 0, stream>>>(cnt, rowptr, bsum, dinv, N);
        k_scan2 <<<1, 128, 0, stream>>>(bsum, nb);
        k_scan3 <<<nb, 256, 0, stream>>>(rowptr, fill, bsum, N, E);
        k_scatter_direct<<<(E + B - 1) / B, B, 0, stream>>>(src, dst, fill, esrc, E);
    }

    k_gemm1 <<<(N + 63) / 64, 256, 0, stream>>>(x, W1, dinv, hb, N);
    k_agg1  <<<(N + 3) / 4, 256, 0, stream>>>(rowptr, esrc, hb, dinv, b1, o1, N);
    k_gemm2 <<<(N + 127) / 128, 128, 0, stream>>>(o1, W2, dinv, h2b, N);
    k_agg2  <<<(N + 63) / 64, 256, 0, stream>>>(rowptr, esrc, h2b, dinv, b2, out, N);
}

// Round 8
// 204.395 us; speedup vs baseline: 3.0026x; 1.0427x over previous
//
#include <hip/hip_runtime.h>

#define NFEAT 128
#define NHID  64
#define NOUT  21
#define BSH   7            // 128 nodes / bucket
#define BCAP  8192         // max edges LDS-sorted per bucket
#define CHUNK 4096         // edges per sort block (16 KB private region)
#define EPT   (CHUNK/256)  // edges per thread in k_lsort
#define PADI  16           // ints per padded counter (64 B)
#define NBUKMAX 1024       // nbuk ceiling for the packed path (N <= 2^17)

typedef unsigned int uint;

// bf16 pack/unpack (RTN-even)
__device__ inline uint packbf2(float a, float b) {
    uint ua = __float_as_uint(a), ub = __float_as_uint(b);
    ua = (ua + 0x7FFFu + ((ua >> 16) & 1u)) >> 16;
    ub = (ub + 0x7FFFu + ((ub >> 16) & 1u)) >> 16;
    return ua | (ub << 16);
}
__device__ inline float bflo(uint v) { return __uint_as_float(v << 16); }
__device__ inline float bfhi(uint v) { return __uint_as_float(v & 0xffff0000u); }

// ============ pass A: per-chunk LDS counting sort by bucket ============

__global__ __launch_bounds__(256) void k_lsort(const int* __restrict__ src, const int* __restrict__ dst,
                                               uint* __restrict__ ebuf, int* __restrict__ tab,
                                               int* __restrict__ gcnt, int E, int nbuk) {
    __shared__ int  lcnt[NBUKMAX + 1];
    __shared__ int  lsum[256];
    __shared__ uint lsorted[CHUNK];
    int c = blockIdx.x, tid = threadIdx.x;
    int base = c * CHUNK;
    int ccnt = min(CHUNK, E - base);

    for (int j = tid; j <= nbuk; j += 256) lcnt[j] = 0;
    __syncthreads();

    int  buk[EPT];
    uint rec[EPT];
#pragma unroll
    for (int k = 0; k < EPT; ++k) {
        int e = base + k * 256 + tid;
        if (e < E) {
            int d = dst[e];
            buk[k] = d >> BSH;
            rec[k] = ((uint)(d & ((1 << BSH) - 1)) << 17) | (uint)src[e];
            atomicAdd(&lcnt[buk[k]], 1);
        }
    }
    __syncthreads();

    int g = (nbuk + 255) / 256;
    int j0 = tid * g;
    int s = 0;
    for (int j = 0; j < g; ++j) { int idx = j0 + j; if (idx < nbuk) s += lcnt[idx]; }
    lsum[tid] = s;
    __syncthreads();
    for (int off = 1; off < 256; off <<= 1) {
        int t = (tid >= off) ? lsum[tid - off] : 0;
        __syncthreads();
        lsum[tid] += t;
        __syncthreads();
    }
    int run = lsum[tid] - s;
    for (int j = 0; j < g; ++j) {
        int idx = j0 + j;
        if (idx < nbuk) { int cv = lcnt[idx]; lcnt[idx] = run; run += cv; }
    }
    __syncthreads();
    if (tid == 0) lcnt[nbuk] = ccnt;
    __syncthreads();

    for (int j = tid; j < nbuk; j += 256) {
        int st = lcnt[j];
        tab[(size_t)c * (nbuk + 1) + j] = st;
        int cj = lcnt[j + 1] - st;
        if (cj) atomicAdd(&gcnt[j * PADI], cj);
    }
    if (tid == 0) tab[(size_t)c * (nbuk + 1) + nbuk] = ccnt;
    __syncthreads();

#pragma unroll
    for (int k = 0; k < EPT; ++k) {
        int e = base + k * 256 + tid;
        if (e < E) {
            int pos = atomicAdd(&lcnt[buk[k]], 1);
            lsorted[pos] = rec[k];
        }
    }
    __syncthreads();
    for (int i = tid; i < ccnt; i += 256) ebuf[base + i] = lsorted[i];
}

// ============ scan bucket totals -> bucket bases ============

__global__ __launch_bounds__(256) void k_bscan(const int* __restrict__ gcnt, int* __restrict__ bbase,
                                               int* __restrict__ rowptr, int nbuk, int N, int E) {
    __shared__ int lv[NBUKMAX];
    __shared__ int lsum[256];
    int tid = threadIdx.x;
    int g = (nbuk + 255) / 256;
    int j0 = tid * g;
    int s = 0;
    for (int j = 0; j < g; ++j) {
        int idx = j0 + j;
        int v = (idx < nbuk) ? gcnt[idx * PADI] : 0;
        if (idx < nbuk) lv[idx] = v;
        s += v;
    }
    lsum[tid] = s;
    __syncthreads();
    for (int off = 1; off < 256; off <<= 1) {
        int t = (tid >= off) ? lsum[tid - off] : 0;
        __syncthreads();
        lsum[tid] += t;
        __syncthreads();
    }
    int run = lsum[tid] - s;
    for (int j = 0; j < g; ++j) {
        int idx = j0 + j;
        if (idx < nbuk) { bbase[idx] = run; run += lv[idx]; }
    }
    if (tid == 0) rowptr[N] = E;
}

// ============ pass B: per-bucket gather + node sort ============

__global__ __launch_bounds__(256) void k_bsort2(const uint* __restrict__ ebuf, const int* __restrict__ tab,
                                                const int* __restrict__ bbase_, const int* __restrict__ gcnt,
                                                int* __restrict__ rowptr, float* __restrict__ dinv,
                                                int* __restrict__ esrc, int nchunk, int nbuk, int N) {
    __shared__ int ncnt[128];
    __shared__ int sc[128];
    __shared__ int lcur[128];
    __shared__ int lsort[BCAP];
    int b = blockIdx.x, tid = threadIdx.x;
    int nb0 = b << BSH;
    int bb = bbase_[b];
    int cnt_b = gcnt[b * PADI];

    if (tid < 128) ncnt[tid] = 0;
    __syncthreads();

    for (int c = tid; c < nchunk; c += 256) {
        const int* trow = tab + (size_t)c * (nbuk + 1);
        int s0 = trow[b], e0 = trow[b + 1];
        const uint* pb = ebuf + (size_t)c * CHUNK;
        for (int i = s0; i < e0; ++i) atomicAdd(&ncnt[pb[i] >> 17], 1);
    }
    __syncthreads();

    int v = (tid < 128) ? ncnt[tid] : 0;
    if (tid < 128) sc[tid] = v;
    __syncthreads();
    for (int off = 1; off < 128; off <<= 1) {
        int t = (tid >= off && tid < 128) ? sc[tid - off] : 0;
        __syncthreads();
        if (tid < 128) sc[tid] += t;
        __syncthreads();
    }
    if (tid < 128) {
        int excl = sc[tid] - v;
        int node = nb0 + tid;
        if (node < N) {
            rowptr[node] = bb + excl;
            dinv[node] = rsqrtf((float)(v + 1));
        }
        lcur[tid] = (cnt_b <= BCAP) ? excl : (bb + excl);
    }
    __syncthreads();

    if (cnt_b <= BCAP) {
        for (int c = tid; c < nchunk; c += 256) {
            const int* trow = tab + (size_t)c * (nbuk + 1);
            int s0 = trow[b], e0 = trow[b + 1];
            const uint* pb = ebuf + (size_t)c * CHUNK;
            for (int i = s0; i < e0; ++i) {
                uint r = pb[i];
                int pos = atomicAdd(&lcur[r >> 17], 1);
                lsort[pos] = (int)(r & 0x1FFFFu);
            }
        }
        __syncthreads();
        for (int i = tid; i < cnt_b; i += 256) esrc[bb + i] = lsort[i];
    } else {
        for (int c = tid; c < nchunk; c += 256) {
            const int* trow = tab + (size_t)c * (nbuk + 1);
            int s0 = trow[b], e0 = trow[b + 1];
            const uint* pb = ebuf + (size_t)c * CHUNK;
            for (int i = s0; i < e0; ++i) {
                uint r = pb[i];
                int pos = atomicAdd(&lcur[r >> 17], 1);
                esrc[pos] = (int)(r & 0x1FFFFu);
            }
        }
    }
}

// ============ general-N fallback (N > 2^17) ============

__global__ __launch_bounds__(256) void k_count(const int* __restrict__ dst, int* cnt, int E) {
    int e = blockIdx.x * 256 + threadIdx.x;
    if (e < E) atomicAdd(&cnt[dst[e]], 1);
}

__global__ __launch_bounds__(256) void k_scan1(const int* __restrict__ cnt, int* __restrict__ rowptr,
                                               int* __restrict__ bsum, float* __restrict__ dinv, int N) {
    __shared__ int sh[256];
    int tid = threadIdx.x;
    int base = blockIdx.x * 1024 + tid * 4;
    int v[4]; int s = 0;
#pragma unroll
    for (int j = 0; j < 4; ++j) {
        v[j] = (base + j < N) ? cnt[base + j] : 0;
        if (base + j < N) dinv[base + j] = rsqrtf((float)(v[j] + 1));
        s += v[j];
    }
    sh[tid] = s; __syncthreads();
    for (int off = 1; off < 256; off <<= 1) {
        int t = (tid >= off) ? sh[tid - off] : 0;
        __syncthreads();
        sh[tid] += t;
        __syncthreads();
    }
    int run = sh[tid] - s;
#pragma unroll
    for (int j = 0; j < 4; ++j) { if (base + j < N) rowptr[base + j] = run; run += v[j]; }
    if (tid == 255) bsum[blockIdx.x] = sh[255];
}

__global__ __launch_bounds__(128) void k_scan2(int* bsum, int nb) {
    __shared__ int sh[128];
    int tid = threadIdx.x;
    int v = (tid < nb) ? bsum[tid] : 0;
    sh[tid] = v; __syncthreads();
    for (int off = 1; off < 128; off <<= 1) {
        int t = (tid >= off) ? sh[tid - off] : 0;
        __syncthreads();
        sh[tid] += t;
        __syncthreads();
    }
    if (tid < nb) bsum[tid] = sh[tid] - v;
}

__global__ __launch_bounds__(256) void k_scan3(int* __restrict__ rowptr, int* __restrict__ fill,
                                               const int* __restrict__ bsum, int N, int E) {
    int tid = threadIdx.x;
    int base = blockIdx.x * 1024 + tid * 4;
    int add = bsum[blockIdx.x];
#pragma unroll
    for (int j = 0; j < 4; ++j) {
        int idx = base + j;
        if (idx < N) {
            int r = rowptr[idx] + add;
            rowptr[idx] = r;
            fill[idx] = r;
        }
    }
    if (blockIdx.x == 0 && tid == 0) rowptr[N] = E;
}

__global__ __launch_bounds__(256) void k_scatter_direct(const int* __restrict__ src, const int* __restrict__ dst,
                                                        int* __restrict__ fill, int* __restrict__ esrc, int E) {
    int e = blockIdx.x * 256 + threadIdx.x;
    if (e >= E) return;
    int pos = atomicAdd(&fill[dst[e]], 1);
    esrc[pos] = src[e];
}

// ===== GEMM1: h' = dinv * (x @ W1), stored packed bf16 [N][32 uints] =====

__global__ __launch_bounds__(256) void k_gemm1(const float* __restrict__ x, const float* __restrict__ W1,
                                               const float* __restrict__ dinv, uint* __restrict__ hb, int N) {
    __shared__ float Ws[NFEAT * NHID];  // 32 KB
    int tid = threadIdx.x;
#pragma unroll
    for (int i = 0; i < 8; ++i) {
        int idx = (tid + i * 256) * 4;
        *(float4*)&Ws[idx] = *(const float4*)&W1[idx];
    }
    __syncthreads();
    int row = blockIdx.x * 64 + (tid >> 2);
    if (row >= N) return;
    int cg = (tid & 3) * 16;
    float acc[16];
#pragma unroll
    for (int j = 0; j < 16; ++j) acc[j] = 0.f;
    const float* xr = x + (size_t)row * NFEAT;
#pragma unroll 4
    for (int k4 = 0; k4 < NFEAT / 4; ++k4) {
        float4 xv = *(const float4*)&xr[k4 * 4];
        float xs[4] = {xv.x, xv.y, xv.z, xv.w};
#pragma unroll
        for (int kk = 0; kk < 4; ++kk) {
            const float* wrow = &Ws[(k4 * 4 + kk) * NHID + cg];
#pragma unroll
            for (int j4 = 0; j4 < 4; ++j4) {
                float4 w = *(const float4*)&wrow[j4 * 4];
                acc[j4 * 4 + 0] = fmaf(xs[kk], w.x, acc[j4 * 4 + 0]);
                acc[j4 * 4 + 1] = fmaf(xs[kk], w.y, acc[j4 * 4 + 1]);
                acc[j4 * 4 + 2] = fmaf(xs[kk], w.z, acc[j4 * 4 + 2]);
                acc[j4 * 4 + 3] = fmaf(xs[kk], w.w, acc[j4 * 4 + 3]);
            }
        }
    }
    float dv = dinv[row];
    uint up[8];
#pragma unroll
    for (int j = 0; j < 8; ++j) up[j] = packbf2(acc[2 * j] * dv, acc[2 * j + 1] * dv);
    uint* hr = hb + (size_t)row * 32 + (tid & 3) * 8;
    ((uint4*)hr)[0] = make_uint4(up[0], up[1], up[2], up[3]);
    ((uint4*)hr)[1] = make_uint4(up[4], up[5], up[6], up[7]);
}

// ===== agg1: o1[d] = relu(b1 + dv_d*(h'[d] + sum_e h'[src_e])) =====
// wave per node; lanes 0-31 even edges / 32-63 odd edges; lane owns 2 feats.
// 4x unroll per half -> 8 independent row-gathers in flight per wave.

__global__ __launch_bounds__(256) void k_agg1(const int* __restrict__ rowptr, const int* __restrict__ esrc,
                                              const uint* __restrict__ hb, const float* __restrict__ dinv,
                                              const float* __restrict__ b1, float* __restrict__ o1, int N) {
    int tid = threadIdx.x;
    int node = blockIdx.x * 4 + (tid >> 6);
    if (node >= N) return;
    int lane = tid & 63;
    int half = lane >> 5;
    int c = lane & 31;
    uint sv = hb[(size_t)node * 32 + c];
    float ax = half ? 0.f : bflo(sv);
    float ay = half ? 0.f : bfhi(sv);
    int beg = rowptr[node], end = rowptr[node + 1];
    int i = beg + half;
    for (; i + 6 < end; i += 8) {
        int s0 = esrc[i], s1 = esrc[i + 2], s2 = esrc[i + 4], s3 = esrc[i + 6];
        uint v0 = hb[(size_t)s0 * 32 + c];
        uint v1 = hb[(size_t)s1 * 32 + c];
        uint v2 = hb[(size_t)s2 * 32 + c];
        uint v3 = hb[(size_t)s3 * 32 + c];
        ax += bflo(v0) + bflo(v1);
        ay += bfhi(v0) + bfhi(v1);
        ax += bflo(v2) + bflo(v3);
        ay += bfhi(v2) + bfhi(v3);
    }
    for (; i < end; i += 2) {
        uint v = hb[(size_t)esrc[i] * 32 + c];
        ax += bflo(v); ay += bfhi(v);
    }
    ax += __shfl_xor(ax, 32);
    ay += __shfl_xor(ay, 32);
    if (!half) {
        float dv = dinv[node];
        float2 bv = ((const float2*)b1)[c];
        float2 r;
        r.x = fmaxf(fmaf(ax, dv, bv.x), 0.f);
        r.y = fmaxf(fmaf(ay, dv, bv.y), 0.f);
        ((float2*)(o1 + (size_t)node * NHID))[c] = r;
    }
}

// ===== GEMM2: h2' = dinv * (o1 @ W2), packed bf16 padded to 24 feats =====

__global__ __launch_bounds__(128) void k_gemm2(const float* __restrict__ o1, const float* __restrict__ W2,
                                               const float* __restrict__ dinv, uint* __restrict__ h2b, int N) {
    __shared__ float rs[128 * 65];
    __shared__ float Ws[NHID * NOUT];
    int tid = threadIdx.x;
    for (int i = tid; i < NHID * NOUT; i += 128) Ws[i] = W2[i];
    int base = blockIdx.x * 128;
#pragma unroll
    for (int i = 0; i < 16; ++i) {
        int idx = tid + i * 128;
        int row = idx >> 4;
        int f4 = (idx & 15) * 4;
        int grow = base + row;
        float4 v = make_float4(0.f, 0.f, 0.f, 0.f);
        if (grow < N) v = *(const float4*)&o1[(size_t)grow * NHID + f4];
        float* d = &rs[row * 65 + f4];
        d[0] = v.x; d[1] = v.y; d[2] = v.z; d[3] = v.w;
    }
    __syncthreads();
    int row = base + tid;
    if (row >= N) return;
    float acc[NOUT];
#pragma unroll
    for (int j = 0; j < NOUT; ++j) acc[j] = 0.f;
    for (int k = 0; k < NHID; ++k) {
        float av = rs[tid * 65 + k];
#pragma unroll
        for (int j = 0; j < NOUT; ++j) acc[j] = fmaf(av, Ws[k * NOUT + j], acc[j]);
    }
    float dv = dinv[row];
    uint up[12];
#pragma unroll
    for (int j = 0; j < 10; ++j) up[j] = packbf2(acc[2 * j] * dv, acc[2 * j + 1] * dv);
    up[10] = packbf2(acc[20] * dv, 0.f);
    up[11] = 0u;
    uint* hr = h2b + (size_t)row * 12;
    ((uint4*)hr)[0] = make_uint4(up[0], up[1], up[2], up[3]);
    ((uint4*)hr)[1] = make_uint4(up[4], up[5], up[6], up[7]);
    ((uint4*)hr)[2] = make_uint4(up[8], up[9], up[10], up[11]);
}

// ===== agg2: out[d] = b2 + dv_d*(h2'[d] + sum_e h2'[src_e]) =====
// 4 lanes per node, lane q owns feats 6q..6q+5 (3 uints); 4x edge unroll.

__global__ __launch_bounds__(256) void k_agg2(const int* __restrict__ rowptr, const int* __restrict__ esrc,
                                              const uint* __restrict__ h2b, const float* __restrict__ dinv,
                                              const float* __restrict__ b2, float* __restrict__ out, int N) {
    int tid = threadIdx.x;
    int node = blockIdx.x * 64 + (tid >> 2);
    if (node >= N) return;
    int q = tid & 3;
    const uint* sp = h2b + (size_t)node * 12 + q * 3;
    uint u0 = sp[0], u1 = sp[1], u2 = sp[2];
    float a0 = bflo(u0), a1 = bfhi(u0), a2 = bflo(u1), a3 = bfhi(u1), a4 = bflo(u2), a5 = bfhi(u2);
    int beg = rowptr[node], end = rowptr[node + 1];
    int i = beg;
    for (; i + 3 < end; i += 4) {
        int s0 = esrc[i], s1 = esrc[i + 1], s2 = esrc[i + 2], s3 = esrc[i + 3];
        const uint* p0 = h2b + (size_t)s0 * 12 + q * 3;
        const uint* p1 = h2b + (size_t)s1 * 12 + q * 3;
        const uint* p2 = h2b + (size_t)s2 * 12 + q * 3;
        const uint* p3 = h2b + (size_t)s3 * 12 + q * 3;
        uint x0 = p0[0], x1 = p0[1], x2 = p0[2];
        uint y0 = p1[0], y1 = p1[1], y2 = p1[2];
        uint z0 = p2[0], z1 = p2[1], z2 = p2[2];
        uint w0 = p3[0], w1 = p3[1], w2 = p3[2];
        a0 += bflo(x0) + bflo(y0); a1 += bfhi(x0) + bfhi(y0);
        a2 += bflo(x1) + bflo(y1); a3 += bfhi(x1) + bfhi(y1);
        a4 += bflo(x2) + bflo(y2); a5 += bfhi(x2) + bfhi(y2);
        a0 += bflo(z0) + bflo(w0); a1 += bfhi(z0) + bfhi(w0);
        a2 += bflo(z1) + bflo(w1); a3 += bfhi(z1) + bfhi(w1);
        a4 += bflo(z2) + bflo(w2); a5 += bfhi(z2) + bfhi(w2);
    }
    for (; i < end; ++i) {
        const uint* p0 = h2b + (size_t)esrc[i] * 12 + q * 3;
        uint x0 = p0[0], x1 = p0[1], x2 = p0[2];
        a0 += bflo(x0); a1 += bfhi(x0);
        a2 += bflo(x1); a3 += bfhi(x1);
        a4 += bflo(x2); a5 += bfhi(x2);
    }
    float dv = dinv[node];
    float* orow = out + (size_t)node * NOUT;
    int col = q * 6;
    float av[6] = {a0, a1, a2, a3, a4, a5};
#pragma unroll
    for (int j = 0; j < 6; ++j)
        if (col + j < NOUT) orow[col + j] = fmaf(dv, av[j], b2[col + j]);
}

// ================= launch =================

extern "C" void kernel_launch(void* const* d_in, const int* in_sizes, int n_in,
                              void* d_out, int out_size, void* d_ws, size_t ws_size,
                              hipStream_t stream) {
    const float* x  = (const float*)d_in[0];
    const int*   ei = (const int*)d_in[1];
    const float* W1 = (const float*)d_in[2];
    const float* b1 = (const float*)d_in[3];
    const float* W2 = (const float*)d_in[4];
    const float* b2 = (const float*)d_in[5];
    float* out = (float*)d_out;

    int N = in_sizes[0] / NFEAT;
    int E = in_sizes[1] / 2;
    const int* src = ei;
    const int* dst = ei + E;
    int NBUK = (N + (1 << BSH) - 1) >> BSH;
    int NCHUNK = (E + CHUNK - 1) / CHUNK;

    char* p = (char*)d_ws;
    auto alloc = [&](size_t bytes) { void* r = (void*)p; p += (bytes + 255) & ~(size_t)255; return r; };
    int*   rowptr = (int*)alloc((size_t)(N + 1) * 4);
    int*   gcnt   = (int*)alloc((size_t)NBUK * PADI * 4);
    int*   bbase  = (int*)alloc((size_t)NBUK * 4);
    int*   tab    = (int*)alloc((size_t)NCHUNK * (NBUK + 1) * 4);
    uint*  ebuf   = (uint*)alloc((size_t)E * 4);
    int*   esrc   = (int*)alloc((size_t)E * 4);
    float* dinv   = (float*)alloc((size_t)N * 4);
    uint*  hb     = (uint*)alloc((size_t)N * 32 * 4);
    float* o1     = (float*)alloc((size_t)N * NHID * 4);
    uint*  h2b    = (uint*)alloc((size_t)N * 12 * 4);
    int*   cnt    = (int*)alloc((size_t)N * 4);      // fallback only
    int*   fill   = (int*)alloc((size_t)N * 4);      // fallback only
    int*   bsum   = (int*)alloc(128 * 4);            // fallback only

    const int B = 256;

    if (N <= (1 << 17)) {
        hipMemsetAsync(gcnt, 0, (size_t)NBUK * PADI * 4, stream);
        k_lsort <<<NCHUNK, 256, 0, stream>>>(src, dst, ebuf, tab, gcnt, E, NBUK);
        k_bscan <<<1, 256, 0, stream>>>(gcnt, bbase, rowptr, NBUK, N, E);
        k_bsort2<<<NBUK, 256, 0, stream>>>(ebuf, tab, bbase, gcnt, rowptr, dinv, esrc, NCHUNK, NBUK, N);
    } else {
        int nb = (N + 1023) / 1024;
        hipMemsetAsync(cnt, 0, (size_t)N * 4, stream);
        k_count <<<(E + B - 1) / B, B, 0, stream>>>(dst, cnt, E);
        k_scan1 <<<nb, 256, 0, stream>>>(cnt, rowptr, bsum, dinv, N);
        k_scan2 <<<1, 128, 0, stream>>>(bsum, nb);
        k_scan3 <<<nb, 256, 0, stream>>>(rowptr, fill, bsum, N, E);
        k_scatter_direct<<<(E + B - 1) / B, B, 0, stream>>>(src, dst, fill, esrc, E);
    }

    k_gemm1 <<<(N + 63) / 64, 256, 0, stream>>>(x, W1, dinv, hb, N);
    k_agg1  <<<(N + 3) / 4, 256, 0, stream>>>(rowptr, esrc, hb, dinv, b1, o1, N);
    k_gemm2 <<<(N + 127) / 128, 128, 0, stream>>>(o1, W2, dinv, h2b, N);
    k_agg2  <<<(N + 63) / 64, 256, 0, stream>>>(rowptr, esrc, h2b, dinv, b2, out, N);
}

// Round 9
// 198.556 us; speedup vs baseline: 3.0909x; 1.0294x over previous
//
#include <hip/hip_runtime.h>

#define NFEAT 128
#define NHID  64
#define NOUT  21
#define BSH   7            // 128 nodes / bucket
#define BCAP  8192         // max edges LDS-sorted per bucket
#define CHUNK 4096         // edges per sort block (16 KB private region)
#define EPT   (CHUNK/256)  // edges per thread in k_lsort
#define PADI  16           // ints per padded counter (64 B)
#define NBUKMAX 1024       // nbuk ceiling for the packed path (N <= 2^17)

typedef unsigned int uint;

// bf16 pack/unpack (RTN-even)
__device__ inline uint packbf2(float a, float b) {
    uint ua = __float_as_uint(a), ub = __float_as_uint(b);
    ua = (ua + 0x7FFFu + ((ua >> 16) & 1u)) >> 16;
    ub = (ub + 0x7FFFu + ((ub >> 16) & 1u)) >> 16;
    return ua | (ub << 16);
}
__device__ inline float bflo(uint v) { return __uint_as_float(v << 16); }
__device__ inline float bfhi(uint v) { return __uint_as_float(v & 0xffff0000u); }

// ============ pass A: per-chunk LDS counting sort by bucket ============

__global__ __launch_bounds__(256) void k_lsort(const int* __restrict__ src, const int* __restrict__ dst,
                                               uint* __restrict__ ebuf, int* __restrict__ tab,
                                               int* __restrict__ gcnt, int E, int nbuk) {
    __shared__ int  lcnt[NBUKMAX + 1];
    __shared__ int  lsum[256];
    __shared__ uint lsorted[CHUNK];
    int c = blockIdx.x, tid = threadIdx.x;
    int base = c * CHUNK;
    int ccnt = min(CHUNK, E - base);

    for (int j = tid; j <= nbuk; j += 256) lcnt[j] = 0;
    __syncthreads();

    int  buk[EPT];
    uint rec[EPT];
#pragma unroll
    for (int k = 0; k < EPT; ++k) {
        int e = base + k * 256 + tid;
        if (e < E) {
            int d = dst[e];
            buk[k] = d >> BSH;
            rec[k] = ((uint)(d & ((1 << BSH) - 1)) << 17) | (uint)src[e];
            atomicAdd(&lcnt[buk[k]], 1);
        }
    }
    __syncthreads();

    int g = (nbuk + 255) / 256;
    int j0 = tid * g;
    int s = 0;
    for (int j = 0; j < g; ++j) { int idx = j0 + j; if (idx < nbuk) s += lcnt[idx]; }
    lsum[tid] = s;
    __syncthreads();
    for (int off = 1; off < 256; off <<= 1) {
        int t = (tid >= off) ? lsum[tid - off] : 0;
        __syncthreads();
        lsum[tid] += t;
        __syncthreads();
    }
    int run = lsum[tid] - s;
    for (int j = 0; j < g; ++j) {
        int idx = j0 + j;
        if (idx < nbuk) { int cv = lcnt[idx]; lcnt[idx] = run; run += cv; }
    }
    __syncthreads();
    if (tid == 0) lcnt[nbuk] = ccnt;
    __syncthreads();

    for (int j = tid; j < nbuk; j += 256) {
        int st = lcnt[j];
        tab[(size_t)c * (nbuk + 1) + j] = st;
        int cj = lcnt[j + 1] - st;
        if (cj) atomicAdd(&gcnt[j * PADI], cj);
    }
    if (tid == 0) tab[(size_t)c * (nbuk + 1) + nbuk] = ccnt;
    __syncthreads();

#pragma unroll
    for (int k = 0; k < EPT; ++k) {
        int e = base + k * 256 + tid;
        if (e < E) {
            int pos = atomicAdd(&lcnt[buk[k]], 1);
            lsorted[pos] = rec[k];
        }
    }
    __syncthreads();
    for (int i = tid; i < ccnt; i += 256) ebuf[base + i] = lsorted[i];
}

// ============ scan bucket totals -> bucket bases ============

__global__ __launch_bounds__(256) void k_bscan(const int* __restrict__ gcnt, int* __restrict__ bbase,
                                               int* __restrict__ rowptr, int nbuk, int N, int E) {
    __shared__ int lv[NBUKMAX];
    __shared__ int lsum[256];
    int tid = threadIdx.x;
    int g = (nbuk + 255) / 256;
    int j0 = tid * g;
    int s = 0;
    for (int j = 0; j < g; ++j) {
        int idx = j0 + j;
        int v = (idx < nbuk) ? gcnt[idx * PADI] : 0;
        if (idx < nbuk) lv[idx] = v;
        s += v;
    }
    lsum[tid] = s;
    __syncthreads();
    for (int off = 1; off < 256; off <<= 1) {
        int t = (tid >= off) ? lsum[tid - off] : 0;
        __syncthreads();
        lsum[tid] += t;
        __syncthreads();
    }
    int run = lsum[tid] - s;
    for (int j = 0; j < g; ++j) {
        int idx = j0 + j;
        if (idx < nbuk) { bbase[idx] = run; run += lv[idx]; }
    }
    if (tid == 0) rowptr[N] = E;
}

// ============ pass B: per-bucket gather + node sort ============

__global__ __launch_bounds__(256) void k_bsort2(const uint* __restrict__ ebuf, const int* __restrict__ tab,
                                                const int* __restrict__ bbase_, const int* __restrict__ gcnt,
                                                int* __restrict__ rowptr, float* __restrict__ dinv,
                                                int* __restrict__ esrc, int nchunk, int nbuk, int N) {
    __shared__ int ncnt[128];
    __shared__ int sc[128];
    __shared__ int lcur[128];
    __shared__ int lsort[BCAP];
    int b = blockIdx.x, tid = threadIdx.x;
    int nb0 = b << BSH;
    int bb = bbase_[b];
    int cnt_b = gcnt[b * PADI];

    if (tid < 128) ncnt[tid] = 0;
    __syncthreads();

    for (int c = tid; c < nchunk; c += 256) {
        const int* trow = tab + (size_t)c * (nbuk + 1);
        int s0 = trow[b], e0 = trow[b + 1];
        const uint* pb = ebuf + (size_t)c * CHUNK;
        for (int i = s0; i < e0; ++i) atomicAdd(&ncnt[pb[i] >> 17], 1);
    }
    __syncthreads();

    int v = (tid < 128) ? ncnt[tid] : 0;
    if (tid < 128) sc[tid] = v;
    __syncthreads();
    for (int off = 1; off < 128; off <<= 1) {
        int t = (tid >= off && tid < 128) ? sc[tid - off] : 0;
        __syncthreads();
        if (tid < 128) sc[tid] += t;
        __syncthreads();
    }
    if (tid < 128) {
        int excl = sc[tid] - v;
        int node = nb0 + tid;
        if (node < N) {
            rowptr[node] = bb + excl;
            dinv[node] = rsqrtf((float)(v + 1));
        }
        lcur[tid] = (cnt_b <= BCAP) ? excl : (bb + excl);
    }
    __syncthreads();

    if (cnt_b <= BCAP) {
        for (int c = tid; c < nchunk; c += 256) {
            const int* trow = tab + (size_t)c * (nbuk + 1);
            int s0 = trow[b], e0 = trow[b + 1];
            const uint* pb = ebuf + (size_t)c * CHUNK;
            for (int i = s0; i < e0; ++i) {
                uint r = pb[i];
                int pos = atomicAdd(&lcur[r >> 17], 1);
                lsort[pos] = (int)(r & 0x1FFFFu);
            }
        }
        __syncthreads();
        for (int i = tid; i < cnt_b; i += 256) esrc[bb + i] = lsort[i];
    } else {
        for (int c = tid; c < nchunk; c += 256) {
            const int* trow = tab + (size_t)c * (nbuk + 1);
            int s0 = trow[b], e0 = trow[b + 1];
            const uint* pb = ebuf + (size_t)c * CHUNK;
            for (int i = s0; i < e0; ++i) {
                uint r = pb[i];
                int pos = atomicAdd(&lcur[r >> 17], 1);
                esrc[pos] = (int)(r & 0x1FFFFu);
            }
        }
    }
}

// ============ general-N fallback (N > 2^17) ============

__global__ __launch_bounds__(256) void k_count(const int* __restrict__ dst, int* cnt, int E) {
    int e = blockIdx.x * 256 + threadIdx.x;
    if (e < E) atomicAdd(&cnt[dst[e]], 1);
}

__global__ __launch_bounds__(256) void k_scan1(const int* __restrict__ cnt, int* __restrict__ rowptr,
                                               int* __restrict__ bsum, float* __restrict__ dinv, int N) {
    __shared__ int sh[256];
    int tid = threadIdx.x;
    int base = blockIdx.x * 1024 + tid * 4;
    int v[4]; int s = 0;
#pragma unroll
    for (int j = 0; j < 4; ++j) {
        v[j] = (base + j < N) ? cnt[base + j] : 0;
        if (base + j < N) dinv[base + j] = rsqrtf((float)(v[j] + 1));
        s += v[j];
    }
    sh[tid] = s; __syncthreads();
    for (int off = 1; off < 256; off <<= 1) {
        int t = (tid >= off) ? sh[tid - off] : 0;
        __syncthreads();
        sh[tid] += t;
        __syncthreads();
    }
    int run = sh[tid] - s;
#pragma unroll
    for (int j = 0; j < 4; ++j) { if (base + j < N) rowptr[base + j] = run; run += v[j]; }
    if (tid == 255) bsum[blockIdx.x] = sh[255];
}

__global__ __launch_bounds__(128) void k_scan2(int* bsum, int nb) {
    __shared__ int sh[128];
    int tid = threadIdx.x;
    int v = (tid < nb) ? bsum[tid] : 0;
    sh[tid] = v; __syncthreads();
    for (int off = 1; off < 128; off <<= 1) {
        int t = (tid >= off) ? sh[tid - off] : 0;
        __syncthreads();
        sh[tid] += t;
        __syncthreads();
    }
    if (tid < nb) bsum[tid] = sh[tid] - v;
}

__global__ __launch_bounds__(256) void k_scan3(int* __restrict__ rowptr, int* __restrict__ fill,
                                               const int* __restrict__ bsum, int N, int E) {
    int tid = threadIdx.x;
    int base = blockIdx.x * 1024 + tid * 4;
    int add = bsum[blockIdx.x];
#pragma unroll
    for (int j = 0; j < 4; ++j) {
        int idx = base + j;
        if (idx < N) {
            int r = rowptr[idx] + add;
            rowptr[idx] = r;
            fill[idx] = r;
        }
    }
    if (blockIdx.x == 0 && tid == 0) rowptr[N] = E;
}

__global__ __launch_bounds__(256) void k_scatter_direct(const int* __restrict__ src, const int* __restrict__ dst,
                                                        int* __restrict__ fill, int* __restrict__ esrc, int E) {
    int e = blockIdx.x * 256 + threadIdx.x;
    if (e >= E) return;
    int pos = atomicAdd(&fill[dst[e]], 1);
    esrc[pos] = src[e];
}

// ===== GEMM1: h' = dinv * (x @ W1), stored packed bf16 [N][32 uints] =====
// 256 thr = 32 rowgrp x 8 colgrp; thread tile = 4 rows x 8 cols.
// Per k4: 8 ds_read_b128 + 4 x-float4 feed 128 FMA -> VALU-bound.

__global__ __launch_bounds__(256) void k_gemm1(const float* __restrict__ x, const float* __restrict__ W1,
                                               const float* __restrict__ dinv, uint* __restrict__ hb, int N) {
    __shared__ float Ws[NFEAT * NHID];  // 32 KB
    int tid = threadIdx.x;
#pragma unroll
    for (int i = 0; i < 8; ++i) {
        int idx = (tid + i * 256) * 4;
        *(float4*)&Ws[idx] = *(const float4*)&W1[idx];
    }
    __syncthreads();
    int cg = (tid & 7) * 8;                       // 8 output cols
    int r0 = blockIdx.x * 128 + (tid >> 3) * 4;   // 4 rows
    if (r0 >= N) return;
    bool full = (r0 + 3 < N);
    float acc[4][8];
#pragma unroll
    for (int r = 0; r < 4; ++r)
#pragma unroll
        for (int j = 0; j < 8; ++j) acc[r][j] = 0.f;
    const float* xr = x + (size_t)r0 * NFEAT;

    for (int k4 = 0; k4 < NFEAT / 4; ++k4) {
        float4 xv[4];
        if (full) {
#pragma unroll
            for (int r = 0; r < 4; ++r) xv[r] = *(const float4*)&xr[r * NFEAT + k4 * 4];
        } else {
#pragma unroll
            for (int r = 0; r < 4; ++r)
                xv[r] = (r0 + r < N) ? *(const float4*)&xr[r * NFEAT + k4 * 4]
                                     : make_float4(0.f, 0.f, 0.f, 0.f);
        }
#pragma unroll
        for (int kk = 0; kk < 4; ++kk) {
            const float* wrow = &Ws[(k4 * 4 + kk) * NHID + cg];
            float4 w0 = *(const float4*)&wrow[0];
            float4 w1 = *(const float4*)&wrow[4];
            float wv[8] = {w0.x, w0.y, w0.z, w0.w, w1.x, w1.y, w1.z, w1.w};
#pragma unroll
            for (int r = 0; r < 4; ++r) {
                float xs = ((const float*)&xv[r])[kk];
#pragma unroll
                for (int j = 0; j < 8; ++j) acc[r][j] = fmaf(xs, wv[j], acc[r][j]);
            }
        }
    }
#pragma unroll
    for (int r = 0; r < 4; ++r) {
        int row = r0 + r;
        if (row >= N) break;
        float dv = dinv[row];
        uint up[4];
#pragma unroll
        for (int j = 0; j < 4; ++j) up[j] = packbf2(acc[r][2 * j] * dv, acc[r][2 * j + 1] * dv);
        *(uint4*)&hb[(size_t)row * 32 + (tid & 7) * 4] = make_uint4(up[0], up[1], up[2], up[3]);
    }
}

// ===== agg1: o1[d] = relu(b1 + dv_d*(h'[d] + sum_e h'[src_e])) =====
// wave per node; lanes 0-31 even edges / 32-63 odd edges; lane owns 2 feats.
// 8x unroll per half -> 16 independent row-gathers in flight per wave.

__global__ __launch_bounds__(256) void k_agg1(const int* __restrict__ rowptr, const int* __restrict__ esrc,
                                              const uint* __restrict__ hb, const float* __restrict__ dinv,
                                              const float* __restrict__ b1, float* __restrict__ o1, int N) {
    int tid = threadIdx.x;
    int node = blockIdx.x * 4 + (tid >> 6);
    if (node >= N) return;
    int lane = tid & 63;
    int half = lane >> 5;
    int c = lane & 31;
    uint sv = hb[(size_t)node * 32 + c];
    float ax = half ? 0.f : bflo(sv);
    float ay = half ? 0.f : bfhi(sv);
    int beg = rowptr[node], end = rowptr[node + 1];
    int i = beg + half;
    for (; i + 14 < end; i += 16) {
        int s0 = esrc[i], s1 = esrc[i + 2], s2 = esrc[i + 4], s3 = esrc[i + 6];
        int s4 = esrc[i + 8], s5 = esrc[i + 10], s6 = esrc[i + 12], s7 = esrc[i + 14];
        uint v0 = hb[(size_t)s0 * 32 + c];
        uint v1 = hb[(size_t)s1 * 32 + c];
        uint v2 = hb[(size_t)s2 * 32 + c];
        uint v3 = hb[(size_t)s3 * 32 + c];
        uint v4 = hb[(size_t)s4 * 32 + c];
        uint v5 = hb[(size_t)s5 * 32 + c];
        uint v6 = hb[(size_t)s6 * 32 + c];
        uint v7 = hb[(size_t)s7 * 32 + c];
        ax += bflo(v0) + bflo(v1);
        ay += bfhi(v0) + bfhi(v1);
        ax += bflo(v2) + bflo(v3);
        ay += bfhi(v2) + bfhi(v3);
        ax += bflo(v4) + bflo(v5);
        ay += bfhi(v4) + bfhi(v5);
        ax += bflo(v6) + bflo(v7);
        ay += bfhi(v6) + bfhi(v7);
    }
    for (; i + 6 < end; i += 8) {
        int s0 = esrc[i], s1 = esrc[i + 2], s2 = esrc[i + 4], s3 = esrc[i + 6];
        uint v0 = hb[(size_t)s0 * 32 + c];
        uint v1 = hb[(size_t)s1 * 32 + c];
        uint v2 = hb[(size_t)s2 * 32 + c];
        uint v3 = hb[(size_t)s3 * 32 + c];
        ax += bflo(v0) + bflo(v1);
        ay += bfhi(v0) + bfhi(v1);
        ax += bflo(v2) + bflo(v3);
        ay += bfhi(v2) + bfhi(v3);
    }
    for (; i < end; i += 2) {
        uint v = hb[(size_t)esrc[i] * 32 + c];
        ax += bflo(v); ay += bfhi(v);
    }
    ax += __shfl_xor(ax, 32);
    ay += __shfl_xor(ay, 32);
    if (!half) {
        float dv = dinv[node];
        float2 bv = ((const float2*)b1)[c];
        float2 r;
        r.x = fmaxf(fmaf(ax, dv, bv.x), 0.f);
        r.y = fmaxf(fmaf(ay, dv, bv.y), 0.f);
        ((float2*)(o1 + (size_t)node * NHID))[c] = r;
    }
}

// ===== GEMM2: h2' = dinv * (o1 @ W2), packed bf16 padded to 24 feats =====

__global__ __launch_bounds__(128) void k_gemm2(const float* __restrict__ o1, const float* __restrict__ W2,
                                               const float* __restrict__ dinv, uint* __restrict__ h2b, int N) {
    __shared__ float rs[128 * 65];
    __shared__ float Ws[NHID * NOUT];
    int tid = threadIdx.x;
    for (int i = tid; i < NHID * NOUT; i += 128) Ws[i] = W2[i];
    int base = blockIdx.x * 128;
#pragma unroll
    for (int i = 0; i < 16; ++i) {
        int idx = tid + i * 128;
        int row = idx >> 4;
        int f4 = (idx & 15) * 4;
        int grow = base + row;
        float4 v = make_float4(0.f, 0.f, 0.f, 0.f);
        if (grow < N) v = *(const float4*)&o1[(size_t)grow * NHID + f4];
        float* d = &rs[row * 65 + f4];
        d[0] = v.x; d[1] = v.y; d[2] = v.z; d[3] = v.w;
    }
    __syncthreads();
    int row = base + tid;
    if (row >= N) return;
    float acc[NOUT];
#pragma unroll
    for (int j = 0; j < NOUT; ++j) acc[j] = 0.f;
    for (int k = 0; k < NHID; ++k) {
        float av = rs[tid * 65 + k];
#pragma unroll
        for (int j = 0; j < NOUT; ++j) acc[j] = fmaf(av, Ws[k * NOUT + j], acc[j]);
    }
    float dv = dinv[row];
    uint up[12];
#pragma unroll
    for (int j = 0; j < 10; ++j) up[j] = packbf2(acc[2 * j] * dv, acc[2 * j + 1] * dv);
    up[10] = packbf2(acc[20] * dv, 0.f);
    up[11] = 0u;
    uint* hr = h2b + (size_t)row * 12;
    ((uint4*)hr)[0] = make_uint4(up[0], up[1], up[2], up[3]);
    ((uint4*)hr)[1] = make_uint4(up[4], up[5], up[6], up[7]);
    ((uint4*)hr)[2] = make_uint4(up[8], up[9], up[10], up[11]);
}

// ===== agg2: out[d] = b2 + dv_d*(h2'[d] + sum_e h2'[src_e]) =====
// 4 lanes per node, lane q owns feats 6q..6q+5 (3 uints); 4x edge unroll.

__global__ __launch_bounds__(256) void k_agg2(const int* __restrict__ rowptr, const int* __restrict__ esrc,
                                              const uint* __restrict__ h2b, const float* __restrict__ dinv,
                                              const float* __restrict__ b2, float* __restrict__ out, int N) {
    int tid = threadIdx.x;
    int node = blockIdx.x * 64 + (tid >> 2);
    if (node >= N) return;
    int q = tid & 3;
    const uint* sp = h2b + (size_t)node * 12 + q * 3;
    uint u0 = sp[0], u1 = sp[1], u2 = sp[2];
    float a0 = bflo(u0), a1 = bfhi(u0), a2 = bflo(u1), a3 = bfhi(u1), a4 = bflo(u2), a5 = bfhi(u2);
    int beg = rowptr[node], end = rowptr[node + 1];
    int i = beg;
    for (; i + 3 < end; i += 4) {
        int s0 = esrc[i], s1 = esrc[i + 1], s2 = esrc[i + 2], s3 = esrc[i + 3];
        const uint* p0 = h2b + (size_t)s0 * 12 + q * 3;
        const uint* p1 = h2b + (size_t)s1 * 12 + q * 3;
        const uint* p2 = h2b + (size_t)s2 * 12 + q * 3;
        const uint* p3 = h2b + (size_t)s3 * 12 + q * 3;
        uint x0 = p0[0], x1 = p0[1], x2 = p0[2];
        uint y0 = p1[0], y1 = p1[1], y2 = p1[2];
        uint z0 = p2[0], z1 = p2[1], z2 = p2[2];
        uint w0 = p3[0], w1 = p3[1], w2 = p3[2];
        a0 += bflo(x0) + bflo(y0); a1 += bfhi(x0) + bfhi(y0);
        a2 += bflo(x1) + bflo(y1); a3 += bfhi(x1) + bfhi(y1);
        a4 += bflo(x2) + bflo(y2); a5 += bfhi(x2) + bfhi(y2);
        a0 += bflo(z0) + bflo(w0); a1 += bfhi(z0) + bfhi(w0);
        a2 += bflo(z1) + bflo(w1); a3 += bfhi(z1) + bfhi(w1);
        a4 += bflo(z2) + bflo(w2); a5 += bfhi(z2) + bfhi(w2);
    }
    for (; i < end; ++i) {
        const uint* p0 = h2b + (size_t)esrc[i] * 12 + q * 3;
        uint x0 = p0[0], x1 = p0[1], x2 = p0[2];
        a0 += bflo(x0); a1 += bfhi(x0);
        a2 += bflo(x1); a3 += bfhi(x1);
        a4 += bflo(x2); a5 += bfhi(x2);
    }
    float dv = dinv[node];
    float* orow = out + (size_t)node * NOUT;
    int col = q * 6;
    float av[6] = {a0, a1, a2, a3, a4, a5};
#pragma unroll
    for (int j = 0; j < 6; ++j)
        if (col + j < NOUT) orow[col + j] = fmaf(dv, av[j], b2[col + j]);
}

// ================= launch =================

extern "C" void kernel_launch(void* const* d_in, const int* in_sizes, int n_in,
                              void* d_out, int out_size, void* d_ws, size_t ws_size,
                              hipStream_t stream) {
    const float* x  = (const float*)d_in[0];
    const int*   ei = (const int*)d_in[1];
    const float* W1 = (const float*)d_in[2];
    const float* b1 = (const float*)d_in[3];
    const float* W2 = (const float*)d_in[4];
    const float* b2 = (const float*)d_in[5];
    float* out = (float*)d_out;

    int N = in_sizes[0] / NFEAT;
    int E = in_sizes[1] / 2;
    const int* src = ei;
    const int* dst = ei + E;
    int NBUK = (N + (1 << BSH) - 1) >> BSH;
    int NCHUNK = (E + CHUNK - 1) / CHUNK;

    char* p = (char*)d_ws;
    auto alloc = [&](size_t bytes) { void* r = (void*)p; p += (bytes + 255) & ~(size_t)255; return r; };
    int*   rowptr = (int*)alloc((size_t)(N + 1) * 4);
    int*   gcnt   = (int*)alloc((size_t)NBUK * PADI * 4);
    int*   bbase  = (int*)alloc((size_t)NBUK * 4);
    int*   tab    = (int*)alloc((size_t)NCHUNK * (NBUK + 1) * 4);
    uint*  ebuf   = (uint*)alloc((size_t)E * 4);
    int*   esrc   = (int*)alloc((size_t)E * 4);
    float* dinv   = (float*)alloc((size_t)N * 4);
    uint*  hb     = (uint*)alloc((size_t)N * 32 * 4);
    float* o1     = (float*)alloc((size_t)N * NHID * 4);
    uint*  h2b    = (uint*)alloc((size_t)N * 12 * 4);
    int*   cnt    = (int*)alloc((size_t)N * 4);      // fallback only
    int*   fill   = (int*)alloc((size_t)N * 4);      // fallback only
    int*   bsum   = (int*)alloc(128 * 4);            // fallback only

    const int B = 256;

    if (N <= (1 << 17)) {
        hipMemsetAsync(gcnt, 0, (size_t)NBUK * PADI * 4, stream);
        k_lsort <<<NCHUNK, 256, 0, stream>>>(src, dst, ebuf, tab, gcnt, E, NBUK);
        k_bscan <<<1, 256, 0, stream>>>(gcnt, bbase, rowptr, NBUK, N, E);
        k_bsort2<<<NBUK, 256, 0, stream>>>(ebuf, tab, bbase, gcnt, rowptr, dinv, esrc, NCHUNK, NBUK, N);
    } else {
        int nb = (N + 1023) / 1024;
        hipMemsetAsync(cnt, 0, (size_t)N * 4, stream);
        k_count <<<(E + B - 1) / B, B, 0, stream>>>(dst, cnt, E);
        k_scan1 <<<nb, 256, 0, stream>>>(cnt, rowptr, bsum, dinv, N);
        k_scan2 <<<1, 128, 0, stream>>>(bsum, nb);
        k_scan3 <<<nb, 256, 0, stream>>>(rowptr, fill, bsum, N, E);
        k_scatter_direct<<<(E + B - 1) / B, B, 0, stream>>>(src, dst, fill, esrc, E);
    }

    k_gemm1 <<<(N + 127) / 128, 256, 0, stream>>>(x, W1, dinv, hb, N);
    k_agg1  <<<(N + 3) / 4, 256, 0, stream>>>(rowptr, esrc, hb, dinv, b1, o1, N);
    k_gemm2 <<<(N + 127) / 128, 128, 0, stream>>>(o1, W2, dinv, h2b, N);
    k_agg2  <<<(N + 63) / 64, 256, 0, stream>>>(rowptr, esrc, h2b, dinv, b2, out, N);
}

// Round 10
// 193.370 us; speedup vs baseline: 3.1738x; 1.0268x over previous
//
#include <hip/hip_runtime.h>

#define NFEAT 128
#define NHID  64
#define NOUT  21
#define BSH   7            // 128 nodes / bucket
#define BCAP  8192         // max edges LDS-sorted per bucket
#define CHUNK 4096         // edges per sort block (16 KB private region)
#define EPT   (CHUNK/256)  // edges per thread in k_lsort
#define PADI  16           // ints per padded counter (64 B)
#define NBUKMAX 1024       // nbuk ceiling for the packed path (N <= 2^17)

typedef unsigned int uint;

// bf16 pack/unpack (RTN-even)
__device__ inline uint packbf2(float a, float b) {
    uint ua = __float_as_uint(a), ub = __float_as_uint(b);
    ua = (ua + 0x7FFFu + ((ua >> 16) & 1u)) >> 16;
    ub = (ub + 0x7FFFu + ((ub >> 16) & 1u)) >> 16;
    return ua | (ub << 16);
}
__device__ inline float bflo(uint v) { return __uint_as_float(v << 16); }
__device__ inline float bfhi(uint v) { return __uint_as_float(v & 0xffff0000u); }

// ============ pass A: per-chunk LDS counting sort by bucket ============

__global__ __launch_bounds__(256) void k_lsort(const int* __restrict__ src, const int* __restrict__ dst,
                                               uint* __restrict__ ebuf, int* __restrict__ tab,
                                               int* __restrict__ gcnt, int E, int nbuk) {
    __shared__ int  lcnt[NBUKMAX + 1];
    __shared__ int  lsum[256];
    __shared__ uint lsorted[CHUNK];
    int c = blockIdx.x, tid = threadIdx.x;
    int base = c * CHUNK;
    int ccnt = min(CHUNK, E - base);

    for (int j = tid; j <= nbuk; j += 256) lcnt[j] = 0;
    __syncthreads();

    int  buk[EPT];
    uint rec[EPT];
#pragma unroll
    for (int k = 0; k < EPT; ++k) {
        int e = base + k * 256 + tid;
        if (e < E) {
            int d = dst[e];
            buk[k] = d >> BSH;
            rec[k] = ((uint)(d & ((1 << BSH) - 1)) << 17) | (uint)src[e];
            atomicAdd(&lcnt[buk[k]], 1);
        }
    }
    __syncthreads();

    int g = (nbuk + 255) / 256;
    int j0 = tid * g;
    int s = 0;
    for (int j = 0; j < g; ++j) { int idx = j0 + j; if (idx < nbuk) s += lcnt[idx]; }
    lsum[tid] = s;
    __syncthreads();
    for (int off = 1; off < 256; off <<= 1) {
        int t = (tid >= off) ? lsum[tid - off] : 0;
        __syncthreads();
        lsum[tid] += t;
        __syncthreads();
    }
    int run = lsum[tid] - s;
    for (int j = 0; j < g; ++j) {
        int idx = j0 + j;
        if (idx < nbuk) { int cv = lcnt[idx]; lcnt[idx] = run; run += cv; }
    }
    __syncthreads();
    if (tid == 0) lcnt[nbuk] = ccnt;
    __syncthreads();

    for (int j = tid; j < nbuk; j += 256) {
        int st = lcnt[j];
        tab[(size_t)c * (nbuk + 1) + j] = st;
        int cj = lcnt[j + 1] - st;
        if (cj) atomicAdd(&gcnt[j * PADI], cj);
    }
    if (tid == 0) tab[(size_t)c * (nbuk + 1) + nbuk] = ccnt;
    __syncthreads();

#pragma unroll
    for (int k = 0; k < EPT; ++k) {
        int e = base + k * 256 + tid;
        if (e < E) {
            int pos = atomicAdd(&lcnt[buk[k]], 1);
            lsorted[pos] = rec[k];
        }
    }
    __syncthreads();
    for (int i = tid; i < ccnt; i += 256) ebuf[base + i] = lsorted[i];
}

// ============ scan bucket totals -> bucket bases ============

__global__ __launch_bounds__(256) void k_bscan(const int* __restrict__ gcnt, int* __restrict__ bbase,
                                               int* __restrict__ rowptr, int nbuk, int N, int E) {
    __shared__ int lv[NBUKMAX];
    __shared__ int lsum[256];
    int tid = threadIdx.x;
    int g = (nbuk + 255) / 256;
    int j0 = tid * g;
    int s = 0;
    for (int j = 0; j < g; ++j) {
        int idx = j0 + j;
        int v = (idx < nbuk) ? gcnt[idx * PADI] : 0;
        if (idx < nbuk) lv[idx] = v;
        s += v;
    }
    lsum[tid] = s;
    __syncthreads();
    for (int off = 1; off < 256; off <<= 1) {
        int t = (tid >= off) ? lsum[tid - off] : 0;
        __syncthreads();
        lsum[tid] += t;
        __syncthreads();
    }
    int run = lsum[tid] - s;
    for (int j = 0; j < g; ++j) {
        int idx = j0 + j;
        if (idx < nbuk) { bbase[idx] = run; run += lv[idx]; }
    }
    if (tid == 0) rowptr[N] = E;
}

// ============ pass B: single-ebuf-pass bucket sort ============
// Pass A: copy bucket's chunk-slices into LDS stash (compacted) + histogram.
// Scan. Pass B: replay stash from LDS, write esrc directly at absolute
// cursors (random within the block-private 8KB region -> L2-absorbed).

__global__ __launch_bounds__(256) void k_bsort2(const uint* __restrict__ ebuf, const int* __restrict__ tab,
                                                const int* __restrict__ bbase_, const int* __restrict__ gcnt,
                                                int* __restrict__ rowptr, float* __restrict__ dinv,
                                                int* __restrict__ esrc, int nchunk, int nbuk, int N) {
    __shared__ int  ncnt[128];
    __shared__ int  sc[128];
    __shared__ int  lcur[128];
    __shared__ uint stash[BCAP];
    __shared__ int  lpos;
    int b = blockIdx.x, tid = threadIdx.x;
    int nb0 = b << BSH;
    int bb = bbase_[b];
    int cnt_b = gcnt[b * PADI];
    bool fits = (cnt_b <= BCAP);

    if (tid < 128) ncnt[tid] = 0;
    if (tid == 0) lpos = 0;
    __syncthreads();

    // pass A: slices -> stash + per-node histogram
    for (int c = tid; c < nchunk; c += 256) {
        const int* trow = tab + (size_t)c * (nbuk + 1);
        int s0 = trow[b], e0 = trow[b + 1];
        int len = e0 - s0;
        if (len <= 0) continue;
        const uint* pb = ebuf + (size_t)c * CHUNK;
        if (fits) {
            int pos = atomicAdd(&lpos, len);
            for (int i = 0; i < len; ++i) {
                uint r = pb[s0 + i];
                stash[pos + i] = r;
                atomicAdd(&ncnt[r >> 17], 1);
            }
        } else {
            for (int i = 0; i < len; ++i) atomicAdd(&ncnt[pb[s0 + i] >> 17], 1);
        }
    }
    __syncthreads();

    // exclusive scan over 128 node counts
    int v = (tid < 128) ? ncnt[tid] : 0;
    if (tid < 128) sc[tid] = v;
    __syncthreads();
    for (int off = 1; off < 128; off <<= 1) {
        int t = (tid >= off && tid < 128) ? sc[tid - off] : 0;
        __syncthreads();
        if (tid < 128) sc[tid] += t;
        __syncthreads();
    }
    if (tid < 128) {
        int excl = sc[tid] - v;
        int node = nb0 + tid;
        if (node < N) {
            rowptr[node] = bb + excl;
            dinv[node] = rsqrtf((float)(v + 1));
        }
        lcur[tid] = bb + excl;              // absolute cursors
    }
    __syncthreads();

    // pass B: place
    if (fits) {
        for (int i = tid; i < cnt_b; i += 256) {
            uint r = stash[i];
            int pos = atomicAdd(&lcur[r >> 17], 1);
            esrc[pos] = (int)(r & 0x1FFFFu);
        }
    } else {
        for (int c = tid; c < nchunk; c += 256) {
            const int* trow = tab + (size_t)c * (nbuk + 1);
            int s0 = trow[b], e0 = trow[b + 1];
            const uint* pb = ebuf + (size_t)c * CHUNK;
            for (int i = s0; i < e0; ++i) {
                uint r = pb[i];
                int pos = atomicAdd(&lcur[r >> 17], 1);
                esrc[pos] = (int)(r & 0x1FFFFu);
            }
        }
    }
}

// ============ general-N fallback (N > 2^17) ============

__global__ __launch_bounds__(256) void k_count(const int* __restrict__ dst, int* cnt, int E) {
    int e = blockIdx.x * 256 + threadIdx.x;
    if (e < E) atomicAdd(&cnt[dst[e]], 1);
}

__global__ __launch_bounds__(256) void k_scan1(const int* __restrict__ cnt, int* __restrict__ rowptr,
                                               int* __restrict__ bsum, float* __restrict__ dinv, int N) {
    __shared__ int sh[256];
    int tid = threadIdx.x;
    int base = blockIdx.x * 1024 + tid * 4;
    int v[4]; int s = 0;
#pragma unroll
    for (int j = 0; j < 4; ++j) {
        v[j] = (base + j < N) ? cnt[base + j] : 0;
        if (base + j < N) dinv[base + j] = rsqrtf((float)(v[j] + 1));
        s += v[j];
    }
    sh[tid] = s; __syncthreads();
    for (int off = 1; off < 256; off <<= 1) {
        int t = (tid >= off) ? sh[tid - off] : 0;
        __syncthreads();
        sh[tid] += t;
        __syncthreads();
    }
    int run = sh[tid] - s;
#pragma unroll
    for (int j = 0; j < 4; ++j) { if (base + j < N) rowptr[base + j] = run; run += v[j]; }
    if (tid == 255) bsum[blockIdx.x] = sh[255];
}

__global__ __launch_bounds__(128) void k_scan2(int* bsum, int nb) {
    __shared__ int sh[128];
    int tid = threadIdx.x;
    int v = (tid < nb) ? bsum[tid] : 0;
    sh[tid] = v; __syncthreads();
    for (int off = 1; off < 128; off <<= 1) {
        int t = (tid >= off) ? sh[tid - off] : 0;
        __syncthreads();
        sh[tid] += t;
        __syncthreads();
    }
    if (tid < nb) bsum[tid] = sh[tid] - v;
}

__global__ __launch_bounds__(256) void k_scan3(int* __restrict__ rowptr, int* __restrict__ fill,
                                               const int* __restrict__ bsum, int N, int E) {
    int tid = threadIdx.x;
    int base = blockIdx.x * 1024 + tid * 4;
    int add = bsum[blockIdx.x];
#pragma unroll
    for (int j = 0; j < 4; ++j) {
        int idx = base + j;
        if (idx < N) {
            int r = rowptr[idx] + add;
            rowptr[idx] = r;
            fill[idx] = r;
        }
    }
    if (blockIdx.x == 0 && tid == 0) rowptr[N] = E;
}

__global__ __launch_bounds__(256) void k_scatter_direct(const int* __restrict__ src, const int* __restrict__ dst,
                                                        int* __restrict__ fill, int* __restrict__ esrc, int E) {
    int e = blockIdx.x * 256 + threadIdx.x;
    if (e >= E) return;
    int pos = atomicAdd(&fill[dst[e]], 1);
    esrc[pos] = src[e];
}

// ===== GEMM1: h' = dinv * (x @ W1), stored packed bf16 [N][32 uints] =====
// 256 thr = 32 rowgrp x 8 colgrp; thread tile = 4 rows x 8 cols.

__global__ __launch_bounds__(256) void k_gemm1(const float* __restrict__ x, const float* __restrict__ W1,
                                               const float* __restrict__ dinv, uint* __restrict__ hb, int N) {
    __shared__ float Ws[NFEAT * NHID];  // 32 KB
    int tid = threadIdx.x;
#pragma unroll
    for (int i = 0; i < 8; ++i) {
        int idx = (tid + i * 256) * 4;
        *(float4*)&Ws[idx] = *(const float4*)&W1[idx];
    }
    __syncthreads();
    int cg = (tid & 7) * 8;                       // 8 output cols
    int r0 = blockIdx.x * 128 + (tid >> 3) * 4;   // 4 rows
    if (r0 >= N) return;
    bool full = (r0 + 3 < N);
    float acc[4][8];
#pragma unroll
    for (int r = 0; r < 4; ++r)
#pragma unroll
        for (int j = 0; j < 8; ++j) acc[r][j] = 0.f;
    const float* xr = x + (size_t)r0 * NFEAT;

    for (int k4 = 0; k4 < NFEAT / 4; ++k4) {
        float4 xv[4];
        if (full) {
#pragma unroll
            for (int r = 0; r < 4; ++r) xv[r] = *(const float4*)&xr[r * NFEAT + k4 * 4];
        } else {
#pragma unroll
            for (int r = 0; r < 4; ++r)
                xv[r] = (r0 + r < N) ? *(const float4*)&xr[r * NFEAT + k4 * 4]
                                     : make_float4(0.f, 0.f, 0.f, 0.f);
        }
#pragma unroll
        for (int kk = 0; kk < 4; ++kk) {
            const float* wrow = &Ws[(k4 * 4 + kk) * NHID + cg];
            float4 w0 = *(const float4*)&wrow[0];
            float4 w1 = *(const float4*)&wrow[4];
            float wv[8] = {w0.x, w0.y, w0.z, w0.w, w1.x, w1.y, w1.z, w1.w};
#pragma unroll
            for (int r = 0; r < 4; ++r) {
                float xs = ((const float*)&xv[r])[kk];
#pragma unroll
                for (int j = 0; j < 8; ++j) acc[r][j] = fmaf(xs, wv[j], acc[r][j]);
            }
        }
    }
#pragma unroll
    for (int r = 0; r < 4; ++r) {
        int row = r0 + r;
        if (row >= N) break;
        float dv = dinv[row];
        uint up[4];
#pragma unroll
        for (int j = 0; j < 4; ++j) up[j] = packbf2(acc[r][2 * j] * dv, acc[r][2 * j + 1] * dv);
        *(uint4*)&hb[(size_t)row * 32 + (tid & 7) * 4] = make_uint4(up[0], up[1], up[2], up[3]);
    }
}

// ===== agg1: o1[d] = relu(b1 + dv_d*(h'[d] + sum_e h'[src_e])) =====

__global__ __launch_bounds__(256) void k_agg1(const int* __restrict__ rowptr, const int* __restrict__ esrc,
                                              const uint* __restrict__ hb, const float* __restrict__ dinv,
                                              const float* __restrict__ b1, float* __restrict__ o1, int N) {
    int tid = threadIdx.x;
    int node = blockIdx.x * 4 + (tid >> 6);
    if (node >= N) return;
    int lane = tid & 63;
    int half = lane >> 5;
    int c = lane & 31;
    uint sv = hb[(size_t)node * 32 + c];
    float ax = half ? 0.f : bflo(sv);
    float ay = half ? 0.f : bfhi(sv);
    int beg = rowptr[node], end = rowptr[node + 1];
    int i = beg + half;
    for (; i + 14 < end; i += 16) {
        int s0 = esrc[i], s1 = esrc[i + 2], s2 = esrc[i + 4], s3 = esrc[i + 6];
        int s4 = esrc[i + 8], s5 = esrc[i + 10], s6 = esrc[i + 12], s7 = esrc[i + 14];
        uint v0 = hb[(size_t)s0 * 32 + c];
        uint v1 = hb[(size_t)s1 * 32 + c];
        uint v2 = hb[(size_t)s2 * 32 + c];
        uint v3 = hb[(size_t)s3 * 32 + c];
        uint v4 = hb[(size_t)s4 * 32 + c];
        uint v5 = hb[(size_t)s5 * 32 + c];
        uint v6 = hb[(size_t)s6 * 32 + c];
        uint v7 = hb[(size_t)s7 * 32 + c];
        ax += bflo(v0) + bflo(v1);
        ay += bfhi(v0) + bfhi(v1);
        ax += bflo(v2) + bflo(v3);
        ay += bfhi(v2) + bfhi(v3);
        ax += bflo(v4) + bflo(v5);
        ay += bfhi(v4) + bfhi(v5);
        ax += bflo(v6) + bflo(v7);
        ay += bfhi(v6) + bfhi(v7);
    }
    for (; i + 6 < end; i += 8) {
        int s0 = esrc[i], s1 = esrc[i + 2], s2 = esrc[i + 4], s3 = esrc[i + 6];
        uint v0 = hb[(size_t)s0 * 32 + c];
        uint v1 = hb[(size_t)s1 * 32 + c];
        uint v2 = hb[(size_t)s2 * 32 + c];
        uint v3 = hb[(size_t)s3 * 32 + c];
        ax += bflo(v0) + bflo(v1);
        ay += bfhi(v0) + bfhi(v1);
        ax += bflo(v2) + bflo(v3);
        ay += bfhi(v2) + bfhi(v3);
    }
    for (; i < end; i += 2) {
        uint v = hb[(size_t)esrc[i] * 32 + c];
        ax += bflo(v); ay += bfhi(v);
    }
    ax += __shfl_xor(ax, 32);
    ay += __shfl_xor(ay, 32);
    if (!half) {
        float dv = dinv[node];
        float2 bv = ((const float2*)b1)[c];
        float2 r;
        r.x = fmaxf(fmaf(ax, dv, bv.x), 0.f);
        r.y = fmaxf(fmaf(ay, dv, bv.y), 0.f);
        ((float2*)(o1 + (size_t)node * NHID))[c] = r;
    }
}

// ===== GEMM2: h2' = dinv * (o1 @ W2), bf16 rows padded to 32 feats (64 B) =====

__global__ __launch_bounds__(128) void k_gemm2(const float* __restrict__ o1, const float* __restrict__ W2,
                                               const float* __restrict__ dinv, uint* __restrict__ h2b, int N) {
    __shared__ float rs[128 * 65];
    __shared__ float Ws[NHID * NOUT];
    int tid = threadIdx.x;
    for (int i = tid; i < NHID * NOUT; i += 128) Ws[i] = W2[i];
    int base = blockIdx.x * 128;
#pragma unroll
    for (int i = 0; i < 16; ++i) {
        int idx = tid + i * 128;
        int row = idx >> 4;
        int f4 = (idx & 15) * 4;
        int grow = base + row;
        float4 v = make_float4(0.f, 0.f, 0.f, 0.f);
        if (grow < N) v = *(const float4*)&o1[(size_t)grow * NHID + f4];
        float* d = &rs[row * 65 + f4];
        d[0] = v.x; d[1] = v.y; d[2] = v.z; d[3] = v.w;
    }
    __syncthreads();
    int row = base + tid;
    if (row >= N) return;
    float acc[NOUT];
#pragma unroll
    for (int j = 0; j < NOUT; ++j) acc[j] = 0.f;
    for (int k = 0; k < NHID; ++k) {
        float av = rs[tid * 65 + k];
#pragma unroll
        for (int j = 0; j < NOUT; ++j) acc[j] = fmaf(av, Ws[k * NOUT + j], acc[j]);
    }
    float dv = dinv[row];
    uint up[16];
#pragma unroll
    for (int j = 0; j < 10; ++j) up[j] = packbf2(acc[2 * j] * dv, acc[2 * j + 1] * dv);
    up[10] = packbf2(acc[20] * dv, 0.f);
#pragma unroll
    for (int j = 11; j < 16; ++j) up[j] = 0u;
    uint* hr = h2b + (size_t)row * 16;
    ((uint4*)hr)[0] = make_uint4(up[0], up[1], up[2], up[3]);
    ((uint4*)hr)[1] = make_uint4(up[4], up[5], up[6], up[7]);
    ((uint4*)hr)[2] = make_uint4(up[8], up[9], up[10], up[11]);
    ((uint4*)hr)[3] = make_uint4(up[12], up[13], up[14], up[15]);
}

// ===== agg2: out[d] = b2 + dv_d*(h2'[d] + sum_e h2'[src_e]) =====
// 4 lanes/node; row = 64 B = 1 line; one dwordx4 per lane per edge; 4x unroll.

__global__ __launch_bounds__(256) void k_agg2(const int* __restrict__ rowptr, const int* __restrict__ esrc,
                                              const uint* __restrict__ h2b, const float* __restrict__ dinv,
                                              const float* __restrict__ b2, float* __restrict__ out, int N) {
    int tid = threadIdx.x;
    int node = blockIdx.x * 64 + (tid >> 2);
    if (node >= N) return;
    int q = tid & 3;
    uint4 sv = *((const uint4*)(h2b + (size_t)node * 16) + q);
    float a0 = bflo(sv.x), a1 = bfhi(sv.x), a2 = bflo(sv.y), a3 = bfhi(sv.y);
    float a4 = bflo(sv.z), a5 = bfhi(sv.z), a6 = bflo(sv.w), a7 = bfhi(sv.w);
    int beg = rowptr[node], end = rowptr[node + 1];
    int i = beg;
    for (; i + 3 < end; i += 4) {
        int s0 = esrc[i], s1 = esrc[i + 1], s2 = esrc[i + 2], s3 = esrc[i + 3];
        uint4 v0 = *((const uint4*)(h2b + (size_t)s0 * 16) + q);
        uint4 v1 = *((const uint4*)(h2b + (size_t)s1 * 16) + q);
        uint4 v2 = *((const uint4*)(h2b + (size_t)s2 * 16) + q);
        uint4 v3 = *((const uint4*)(h2b + (size_t)s3 * 16) + q);
        a0 += bflo(v0.x) + bflo(v1.x);
        a1 += bfhi(v0.x) + bfhi(v1.x);
        a2 += bflo(v0.y) + bflo(v1.y);
        a3 += bfhi(v0.y) + bfhi(v1.y);
        a4 += bflo(v0.z) + bflo(v1.z);
        a5 += bfhi(v0.z) + bfhi(v1.z);
        a6 += bflo(v0.w) + bflo(v1.w);
        a7 += bfhi(v0.w) + bfhi(v1.w);
        a0 += bflo(v2.x) + bflo(v3.x);
        a1 += bfhi(v2.x) + bfhi(v3.x);
        a2 += bflo(v2.y) + bflo(v3.y);
        a3 += bfhi(v2.y) + bfhi(v3.y);
        a4 += bflo(v2.z) + bflo(v3.z);
        a5 += bfhi(v2.z) + bfhi(v3.z);
        a6 += bflo(v2.w) + bflo(v3.w);
        a7 += bfhi(v2.w) + bfhi(v3.w);
    }
    for (; i < end; ++i) {
        uint4 v0 = *((const uint4*)(h2b + (size_t)esrc[i] * 16) + q);
        a0 += bflo(v0.x); a1 += bfhi(v0.x);
        a2 += bflo(v0.y); a3 += bfhi(v0.y);
        a4 += bflo(v0.z); a5 += bfhi(v0.z);
        a6 += bflo(v0.w); a7 += bfhi(v0.w);
    }
    float dv = dinv[node];
    float* orow = out + (size_t)node * NOUT;
    int col = q * 8;
    float av[8] = {a0, a1, a2, a3, a4, a5, a6, a7};
#pragma unroll
    for (int j = 0; j < 8; ++j)
        if (col + j < NOUT) orow[col + j] = fmaf(dv, av[j], b2[col + j]);
}

// ================= launch =================

extern "C" void kernel_launch(void* const* d_in, const int* in_sizes, int n_in,
                              void* d_out, int out_size, void* d_ws, size_t ws_size,
                              hipStream_t stream) {
    const float* x  = (const float*)d_in[0];
    const int*   ei = (const int*)d_in[1];
    const float* W1 = (const float*)d_in[2];
    const float* b1 = (const float*)d_in[3];
    const float* W2 = (const float*)d_in[4];
    const float* b2 = (const float*)d_in[5];
    float* out = (float*)d_out;

    int N = in_sizes[0] / NFEAT;
    int E = in_sizes[1] / 2;
    const int* src = ei;
    const int* dst = ei + E;
    int NBUK = (N + (1 << BSH) - 1) >> BSH;
    int NCHUNK = (E + CHUNK - 1) / CHUNK;

    char* p = (char*)d_ws;
    auto alloc = [&](size_t bytes) { void* r = (void*)p; p += (bytes + 255) & ~(size_t)255; return r; };
    int*   rowptr = (int*)alloc((size_t)(N + 1) * 4);
    int*   gcnt   = (int*)alloc((size_t)NBUK * PADI * 4);
    int*   bbase  = (int*)alloc((size_t)NBUK * 4);
    int*   tab    = (int*)alloc((size_t)NCHUNK * (NBUK + 1) * 4);
    uint*  ebuf   = (uint*)alloc((size_t)E * 4);
    int*   esrc   = (int*)alloc((size_t)E * 4);
    float* dinv   = (float*)alloc((size_t)N * 4);
    uint*  hb     = (uint*)alloc((size_t)N * 32 * 4);
    float* o1     = (float*)alloc((size_t)N * NHID * 4);
    uint*  h2b    = (uint*)alloc((size_t)N * 16 * 4);   // bf16 rows padded to 64 B
    int*   cnt    = (int*)alloc((size_t)N * 4);      // fallback only
    int*   fill   = (int*)alloc((size_t)N * 4);      // fallback only
    int*   bsum   = (int*)alloc(128 * 4);            // fallback only

    const int B = 256;

    if (N <= (1 << 17)) {
        hipMemsetAsync(gcnt, 0, (size_t)NBUK * PADI * 4, stream);
        k_lsort <<<NCHUNK, 256, 0, stream>>>(src, dst, ebuf, tab, gcnt, E, NBUK);
        k_bscan <<<1, 256, 0, stream>>>(gcnt, bbase, rowptr, NBUK, N, E);
        k_bsort2<<<NBUK, 256, 0, stream>>>(ebuf, tab, bbase, gcnt, rowptr, dinv, esrc, NCHUNK, NBUK, N);
    } else {
        int nb = (N + 1023) / 1024;
        hipMemsetAsync(cnt, 0, (size_t)N * 4, stream);
        k_count <<<(E + B - 1) / B, B, 0, stream>>>(dst, cnt, E);
        k_scan1 <<<nb, 256, 0, stream>>>(cnt, rowptr, bsum, dinv, N);
        k_scan2 <<<1, 128, 0, stream>>>(bsum, nb);
        k_scan3 <<<nb, 256, 0, stream>>>(rowptr, fill, bsum, N, E);
        k_scatter_direct<<<(E + B - 1) / B, B, 0, stream>>>(src, dst, fill, esrc, E);
    }

    k_gemm1 <<<(N + 127) / 128, 256, 0, stream>>>(x, W1, dinv, hb, N);
    k_agg1  <<<(N + 3) / 4, 256, 0, stream>>>(rowptr, esrc, hb, dinv, b1, o1, N);
    k_gemm2 <<<(N + 127) / 128, 128, 0, stream>>>(o1, W2, dinv, h2b, N);
    k_agg2  <<<(N + 63) / 64, 256, 0, stream>>>(rowptr, esrc, h2b, dinv, b2, out, N);
}

// Round 11
// 177.202 us; speedup vs baseline: 3.4633x; 1.0912x over previous
//
#include <hip/hip_runtime.h>

#define NFEAT 128
#define NHID  64
#define NOUT  21
#define BSH   7            // 128 nodes / bucket
#define BCAP  8192         // max edges LDS-sorted per bucket
#define CHUNK 4096         // edges per sort block (16 KB private region)
#define EPT   (CHUNK/256)  // edges per thread in k_lsort
#define PADI  16           // ints per padded counter (64 B)
#define NBUKMAX 1024       // nbuk ceiling for the packed path (N <= 2^17)

typedef unsigned int uint;
typedef unsigned short ushort_t;

typedef __bf16 bf16_t;
typedef bf16_t bf16x8 __attribute__((ext_vector_type(8)));
typedef float  f32x4  __attribute__((ext_vector_type(4)));

// bf16 pack/unpack (RTN-even)
__device__ inline uint packbf2(float a, float b) {
    uint ua = __float_as_uint(a), ub = __float_as_uint(b);
    ua = (ua + 0x7FFFu + ((ua >> 16) & 1u)) >> 16;
    ub = (ub + 0x7FFFu + ((ub >> 16) & 1u)) >> 16;
    return ua | (ub << 16);
}
__device__ inline float bflo(uint v) { return __uint_as_float(v << 16); }
__device__ inline float bfhi(uint v) { return __uint_as_float(v & 0xffff0000u); }

// ============ pass A: per-chunk LDS counting sort by bucket ============

__global__ __launch_bounds__(256) void k_lsort(const int* __restrict__ src, const int* __restrict__ dst,
                                               uint* __restrict__ ebuf, int* __restrict__ tab,
                                               int* __restrict__ gcnt, int E, int nbuk) {
    __shared__ int  lcnt[NBUKMAX + 1];
    __shared__ int  lsum[256];
    __shared__ uint lsorted[CHUNK];
    int c = blockIdx.x, tid = threadIdx.x;
    int base = c * CHUNK;
    int ccnt = min(CHUNK, E - base);

    for (int j = tid; j <= nbuk; j += 256) lcnt[j] = 0;
    __syncthreads();

    int  buk[EPT];
    uint rec[EPT];
#pragma unroll
    for (int k = 0; k < EPT; ++k) {
        int e = base + k * 256 + tid;
        if (e < E) {
            int d = dst[e];
            buk[k] = d >> BSH;
            rec[k] = ((uint)(d & ((1 << BSH) - 1)) << 17) | (uint)src[e];
            atomicAdd(&lcnt[buk[k]], 1);
        }
    }
    __syncthreads();

    int g = (nbuk + 255) / 256;
    int j0 = tid * g;
    int s = 0;
    for (int j = 0; j < g; ++j) { int idx = j0 + j; if (idx < nbuk) s += lcnt[idx]; }
    lsum[tid] = s;
    __syncthreads();
    for (int off = 1; off < 256; off <<= 1) {
        int t = (tid >= off) ? lsum[tid - off] : 0;
        __syncthreads();
        lsum[tid] += t;
        __syncthreads();
    }
    int run = lsum[tid] - s;
    for (int j = 0; j < g; ++j) {
        int idx = j0 + j;
        if (idx < nbuk) { int cv = lcnt[idx]; lcnt[idx] = run; run += cv; }
    }
    __syncthreads();
    if (tid == 0) lcnt[nbuk] = ccnt;
    __syncthreads();

    for (int j = tid; j < nbuk; j += 256) {
        int st = lcnt[j];
        tab[(size_t)c * (nbuk + 1) + j] = st;
        int cj = lcnt[j + 1] - st;
        if (cj) atomicAdd(&gcnt[j * PADI], cj);
    }
    if (tid == 0) tab[(size_t)c * (nbuk + 1) + nbuk] = ccnt;
    __syncthreads();

#pragma unroll
    for (int k = 0; k < EPT; ++k) {
        int e = base + k * 256 + tid;
        if (e < E) {
            int pos = atomicAdd(&lcnt[buk[k]], 1);
            lsorted[pos] = rec[k];
        }
    }
    __syncthreads();
    for (int i = tid; i < ccnt; i += 256) ebuf[base + i] = lsorted[i];
}

// ============ scan bucket totals -> bucket bases ============

__global__ __launch_bounds__(256) void k_bscan(const int* __restrict__ gcnt, int* __restrict__ bbase,
                                               int* __restrict__ rowptr, int nbuk, int N, int E) {
    __shared__ int lv[NBUKMAX];
    __shared__ int lsum[256];
    int tid = threadIdx.x;
    int g = (nbuk + 255) / 256;
    int j0 = tid * g;
    int s = 0;
    for (int j = 0; j < g; ++j) {
        int idx = j0 + j;
        int v = (idx < nbuk) ? gcnt[idx * PADI] : 0;
        if (idx < nbuk) lv[idx] = v;
        s += v;
    }
    lsum[tid] = s;
    __syncthreads();
    for (int off = 1; off < 256; off <<= 1) {
        int t = (tid >= off) ? lsum[tid - off] : 0;
        __syncthreads();
        lsum[tid] += t;
        __syncthreads();
    }
    int run = lsum[tid] - s;
    for (int j = 0; j < g; ++j) {
        int idx = j0 + j;
        if (idx < nbuk) { bbase[idx] = run; run += lv[idx]; }
    }
    if (tid == 0) rowptr[N] = E;
}

// ============ pass B: single-ebuf-pass bucket sort ============

__global__ __launch_bounds__(256) void k_bsort2(const uint* __restrict__ ebuf, const int* __restrict__ tab,
                                                const int* __restrict__ bbase_, const int* __restrict__ gcnt,
                                                int* __restrict__ rowptr, float* __restrict__ dinv,
                                                int* __restrict__ esrc, int nchunk, int nbuk, int N) {
    __shared__ int  ncnt[128];
    __shared__ int  sc[128];
    __shared__ int  lcur[128];
    __shared__ uint stash[BCAP];
    __shared__ int  lpos;
    int b = blockIdx.x, tid = threadIdx.x;
    int nb0 = b << BSH;
    int bb = bbase_[b];
    int cnt_b = gcnt[b * PADI];
    bool fits = (cnt_b <= BCAP);

    if (tid < 128) ncnt[tid] = 0;
    if (tid == 0) lpos = 0;
    __syncthreads();

    for (int c = tid; c < nchunk; c += 256) {
        const int* trow = tab + (size_t)c * (nbuk + 1);
        int s0 = trow[b], e0 = trow[b + 1];
        int len = e0 - s0;
        if (len <= 0) continue;
        const uint* pb = ebuf + (size_t)c * CHUNK;
        if (fits) {
            int pos = atomicAdd(&lpos, len);
            for (int i = 0; i < len; ++i) {
                uint r = pb[s0 + i];
                stash[pos + i] = r;
                atomicAdd(&ncnt[r >> 17], 1);
            }
        } else {
            for (int i = 0; i < len; ++i) atomicAdd(&ncnt[pb[s0 + i] >> 17], 1);
        }
    }
    __syncthreads();

    int v = (tid < 128) ? ncnt[tid] : 0;
    if (tid < 128) sc[tid] = v;
    __syncthreads();
    for (int off = 1; off < 128; off <<= 1) {
        int t = (tid >= off && tid < 128) ? sc[tid - off] : 0;
        __syncthreads();
        if (tid < 128) sc[tid] += t;
        __syncthreads();
    }
    if (tid < 128) {
        int excl = sc[tid] - v;
        int node = nb0 + tid;
        if (node < N) {
            rowptr[node] = bb + excl;
            dinv[node] = rsqrtf((float)(v + 1));
        }
        lcur[tid] = bb + excl;
    }
    __syncthreads();

    if (fits) {
        for (int i = tid; i < cnt_b; i += 256) {
            uint r = stash[i];
            int pos = atomicAdd(&lcur[r >> 17], 1);
            esrc[pos] = (int)(r & 0x1FFFFu);
        }
    } else {
        for (int c = tid; c < nchunk; c += 256) {
            const int* trow = tab + (size_t)c * (nbuk + 1);
            int s0 = trow[b], e0 = trow[b + 1];
            const uint* pb = ebuf + (size_t)c * CHUNK;
            for (int i = s0; i < e0; ++i) {
                uint r = pb[i];
                int pos = atomicAdd(&lcur[r >> 17], 1);
                esrc[pos] = (int)(r & 0x1FFFFu);
            }
        }
    }
}

// ============ general-N fallback (N > 2^17) ============

__global__ __launch_bounds__(256) void k_count(const int* __restrict__ dst, int* cnt, int E) {
    int e = blockIdx.x * 256 + threadIdx.x;
    if (e < E) atomicAdd(&cnt[dst[e]], 1);
}

__global__ __launch_bounds__(256) void k_scan1(const int* __restrict__ cnt, int* __restrict__ rowptr,
                                               int* __restrict__ bsum, float* __restrict__ dinv, int N) {
    __shared__ int sh[256];
    int tid = threadIdx.x;
    int base = blockIdx.x * 1024 + tid * 4;
    int v[4]; int s = 0;
#pragma unroll
    for (int j = 0; j < 4; ++j) {
        v[j] = (base + j < N) ? cnt[base + j] : 0;
        if (base + j < N) dinv[base + j] = rsqrtf((float)(v[j] + 1));
        s += v[j];
    }
    sh[tid] = s; __syncthreads();
    for (int off = 1; off < 256; off <<= 1) {
        int t = (tid >= off) ? sh[tid - off] : 0;
        __syncthreads();
        sh[tid] += t;
        __syncthreads();
    }
    int run = sh[tid] - s;
#pragma unroll
    for (int j = 0; j < 4; ++j) { if (base + j < N) rowptr[base + j] = run; run += v[j]; }
    if (tid == 255) bsum[blockIdx.x] = sh[255];
}

__global__ __launch_bounds__(128) void k_scan2(int* bsum, int nb) {
    __shared__ int sh[128];
    int tid = threadIdx.x;
    int v = (tid < nb) ? bsum[tid] : 0;
    sh[tid] = v; __syncthreads();
    for (int off = 1; off < 128; off <<= 1) {
        int t = (tid >= off) ? sh[tid - off] : 0;
        __syncthreads();
        sh[tid] += t;
        __syncthreads();
    }
    if (tid < nb) bsum[tid] = sh[tid] - v;
}

__global__ __launch_bounds__(256) void k_scan3(int* __restrict__ rowptr, int* __restrict__ fill,
                                               const int* __restrict__ bsum, int N, int E) {
    int tid = threadIdx.x;
    int base = blockIdx.x * 1024 + tid * 4;
    int add = bsum[blockIdx.x];
#pragma unroll
    for (int j = 0; j < 4; ++j) {
        int idx = base + j;
        if (idx < N) {
            int r = rowptr[idx] + add;
            rowptr[idx] = r;
            fill[idx] = r;
        }
    }
    if (blockIdx.x == 0 && tid == 0) rowptr[N] = E;
}

__global__ __launch_bounds__(256) void k_scatter_direct(const int* __restrict__ src, const int* __restrict__ dst,
                                                        int* __restrict__ fill, int* __restrict__ esrc, int E) {
    int e = blockIdx.x * 256 + threadIdx.x;
    if (e >= E) return;
    int pos = atomicAdd(&fill[dst[e]], 1);
    esrc[pos] = src[e];
}

// ===== GEMM1 via MFMA: h' = dinv * (x @ W1), bf16 in, f32 accum, bf16 out =====
// Block = 64 rows x 64 cols, 4 waves (16 rows each). K=128 in 4 steps of 32.
// A frag: row=lane&15, k=(lane>>4)*8+j. B frag: col=lane&15, same k.
// C/D: col=lane&15, row=(lane>>4)*4+reg  [measured m89].
// LDS rows padded to 136 ushorts (272 B) to break 256B-stride bank conflicts.

__global__ __launch_bounds__(256) void k_gemm1(const float* __restrict__ x, const float* __restrict__ W1,
                                               const float* __restrict__ dinv, uint* __restrict__ hb, int N) {
    __shared__ ushort_t xs[64 * 136];   // x tile bf16 [row][k]
    __shared__ ushort_t ws[64 * 136];   // W1^T bf16 [col][k]
    int tid = threadIdx.x;
    int r0 = blockIdx.x * 64;

    // stage W1^T: thread t -> col = t&63, k-range (t>>6)*32
    {
        int col = tid & 63;
        int kb = (tid >> 6) * 32;
#pragma unroll
        for (int kk = 0; kk < 32; kk += 2) {
            float a = W1[(size_t)(kb + kk) * NHID + col];
            float b = W1[(size_t)(kb + kk + 1) * NHID + col];
            *(uint*)&ws[col * 136 + kb + kk] = packbf2(a, b);
        }
    }
    // stage x tile: thread t -> row = t>>2, quarter q = t&3 (32 floats)
    {
        int row = tid >> 2;
        int q = tid & 3;
        int grow = r0 + row;
        uint buf[16];
        if (grow < N) {
            const float* xr = x + (size_t)grow * NFEAT + q * 32;
#pragma unroll
            for (int j = 0; j < 8; ++j) {
                float4 v = *(const float4*)&xr[j * 4];
                buf[2 * j]     = packbf2(v.x, v.y);
                buf[2 * j + 1] = packbf2(v.z, v.w);
            }
        } else {
#pragma unroll
            for (int j = 0; j < 16; ++j) buf[j] = 0u;
        }
        uint* d = (uint*)&xs[row * 136 + q * 32];
#pragma unroll
        for (int j = 0; j < 4; ++j)
            ((uint4*)d)[j] = make_uint4(buf[4 * j], buf[4 * j + 1], buf[4 * j + 2], buf[4 * j + 3]);
    }
    __syncthreads();

    int lane = tid & 63;
    int wrow = (tid >> 6) * 16;        // wave's 16-row sub-tile
    int lrow = lane & 15;
    int lk   = (lane >> 4) * 8;

    f32x4 acc[4];
#pragma unroll
    for (int nt = 0; nt < 4; ++nt) acc[nt] = (f32x4){0.f, 0.f, 0.f, 0.f};

#pragma unroll
    for (int kq = 0; kq < 4; ++kq) {
        int k0 = kq * 32;
        bf16x8 a = *(const bf16x8*)&xs[(wrow + lrow) * 136 + k0 + lk];
#pragma unroll
        for (int nt = 0; nt < 4; ++nt) {
            bf16x8 b = *(const bf16x8*)&ws[(nt * 16 + lrow) * 136 + k0 + lk];
            acc[nt] = __builtin_amdgcn_mfma_f32_16x16x32_bf16(a, b, acc[nt], 0, 0, 0);
        }
    }

    // epilogue: scale by dinv[row], pack bf16, scattered ushort stores
    int orow0 = (lane >> 4) * 4;
    float dvv[4];
#pragma unroll
    for (int r = 0; r < 4; ++r) {
        int grow = r0 + wrow + orow0 + r;
        dvv[r] = (grow < N) ? dinv[grow] : 0.f;
    }
    ushort_t* hbs = (ushort_t*)hb;
#pragma unroll
    for (int nt = 0; nt < 4; ++nt) {
#pragma unroll
        for (int r = 0; r < 4; ++r) {
            int grow = r0 + wrow + orow0 + r;
            if (grow < N) {
                uint pb = packbf2(acc[nt][r] * dvv[r], 0.f);
                hbs[(size_t)grow * 64 + nt * 16 + lrow] = (ushort_t)(pb & 0xffffu);
            }
        }
    }
}

// ===== agg1: o1[d] = relu(b1 + dv_d*(h'[d] + sum_e h'[src_e])) =====

__global__ __launch_bounds__(256) void k_agg1(const int* __restrict__ rowptr, const int* __restrict__ esrc,
                                              const uint* __restrict__ hb, const float* __restrict__ dinv,
                                              const float* __restrict__ b1, float* __restrict__ o1, int N) {
    int tid = threadIdx.x;
    int node = blockIdx.x * 4 + (tid >> 6);
    if (node >= N) return;
    int lane = tid & 63;
    int half = lane >> 5;
    int c = lane & 31;
    uint sv = hb[(size_t)node * 32 + c];
    float ax = half ? 0.f : bflo(sv);
    float ay = half ? 0.f : bfhi(sv);
    int beg = rowptr[node], end = rowptr[node + 1];
    int i = beg + half;
    for (; i + 14 < end; i += 16) {
        int s0 = esrc[i], s1 = esrc[i + 2], s2 = esrc[i + 4], s3 = esrc[i + 6];
        int s4 = esrc[i + 8], s5 = esrc[i + 10], s6 = esrc[i + 12], s7 = esrc[i + 14];
        uint v0 = hb[(size_t)s0 * 32 + c];
        uint v1 = hb[(size_t)s1 * 32 + c];
        uint v2 = hb[(size_t)s2 * 32 + c];
        uint v3 = hb[(size_t)s3 * 32 + c];
        uint v4 = hb[(size_t)s4 * 32 + c];
        uint v5 = hb[(size_t)s5 * 32 + c];
        uint v6 = hb[(size_t)s6 * 32 + c];
        uint v7 = hb[(size_t)s7 * 32 + c];
        ax += bflo(v0) + bflo(v1);
        ay += bfhi(v0) + bfhi(v1);
        ax += bflo(v2) + bflo(v3);
        ay += bfhi(v2) + bfhi(v3);
        ax += bflo(v4) + bflo(v5);
        ay += bfhi(v4) + bfhi(v5);
        ax += bflo(v6) + bflo(v7);
        ay += bfhi(v6) + bfhi(v7);
    }
    for (; i + 6 < end; i += 8) {
        int s0 = esrc[i], s1 = esrc[i + 2], s2 = esrc[i + 4], s3 = esrc[i + 6];
        uint v0 = hb[(size_t)s0 * 32 + c];
        uint v1 = hb[(size_t)s1 * 32 + c];
        uint v2 = hb[(size_t)s2 * 32 + c];
        uint v3 = hb[(size_t)s3 * 32 + c];
        ax += bflo(v0) + bflo(v1);
        ay += bfhi(v0) + bfhi(v1);
        ax += bflo(v2) + bflo(v3);
        ay += bfhi(v2) + bfhi(v3);
    }
    for (; i < end; i += 2) {
        uint v = hb[(size_t)esrc[i] * 32 + c];
        ax += bflo(v); ay += bfhi(v);
    }
    ax += __shfl_xor(ax, 32);
    ay += __shfl_xor(ay, 32);
    if (!half) {
        float dv = dinv[node];
        float2 bv = ((const float2*)b1)[c];
        float2 r;
        r.x = fmaxf(fmaf(ax, dv, bv.x), 0.f);
        r.y = fmaxf(fmaf(ay, dv, bv.y), 0.f);
        ((float2*)(o1 + (size_t)node * NHID))[c] = r;
    }
}

// ===== GEMM2: h2' = dinv * (o1 @ W2), bf16 rows padded to 32 feats (64 B) =====

__global__ __launch_bounds__(128) void k_gemm2(const float* __restrict__ o1, const float* __restrict__ W2,
                                               const float* __restrict__ dinv, uint* __restrict__ h2b, int N) {
    __shared__ float rs[128 * 65];
    __shared__ float Ws[NHID * NOUT];
    int tid = threadIdx.x;
    for (int i = tid; i < NHID * NOUT; i += 128) Ws[i] = W2[i];
    int base = blockIdx.x * 128;
#pragma unroll
    for (int i = 0; i < 16; ++i) {
        int idx = tid + i * 128;
        int row = idx >> 4;
        int f4 = (idx & 15) * 4;
        int grow = base + row;
        float4 v = make_float4(0.f, 0.f, 0.f, 0.f);
        if (grow < N) v = *(const float4*)&o1[(size_t)grow * NHID + f4];
        float* d = &rs[row * 65 + f4];
        d[0] = v.x; d[1] = v.y; d[2] = v.z; d[3] = v.w;
    }
    __syncthreads();
    int row = base + tid;
    if (row >= N) return;
    float acc[NOUT];
#pragma unroll
    for (int j = 0; j < NOUT; ++j) acc[j] = 0.f;
    for (int k = 0; k < NHID; ++k) {
        float av = rs[tid * 65 + k];
#pragma unroll
        for (int j = 0; j < NOUT; ++j) acc[j] = fmaf(av, Ws[k * NOUT + j], acc[j]);
    }
    float dv = dinv[row];
    uint up[16];
#pragma unroll
    for (int j = 0; j < 10; ++j) up[j] = packbf2(acc[2 * j] * dv, acc[2 * j + 1] * dv);
    up[10] = packbf2(acc[20] * dv, 0.f);
#pragma unroll
    for (int j = 11; j < 16; ++j) up[j] = 0u;
    uint* hr = h2b + (size_t)row * 16;
    ((uint4*)hr)[0] = make_uint4(up[0], up[1], up[2], up[3]);
    ((uint4*)hr)[1] = make_uint4(up[4], up[5], up[6], up[7]);
    ((uint4*)hr)[2] = make_uint4(up[8], up[9], up[10], up[11]);
    ((uint4*)hr)[3] = make_uint4(up[12], up[13], up[14], up[15]);
}

// ===== agg2: out[d] = b2 + dv_d*(h2'[d] + sum_e h2'[src_e]) =====

__global__ __launch_bounds__(256) void k_agg2(const int* __restrict__ rowptr, const int* __restrict__ esrc,
                                              const uint* __restrict__ h2b, const float* __restrict__ dinv,
                                              const float* __restrict__ b2, float* __restrict__ out, int N) {
    int tid = threadIdx.x;
    int node = blockIdx.x * 64 + (tid >> 2);
    if (node >= N) return;
    int q = tid & 3;
    uint4 sv = *((const uint4*)(h2b + (size_t)node * 16) + q);
    float a0 = bflo(sv.x), a1 = bfhi(sv.x), a2 = bflo(sv.y), a3 = bfhi(sv.y);
    float a4 = bflo(sv.z), a5 = bfhi(sv.z), a6 = bflo(sv.w), a7 = bfhi(sv.w);
    int beg = rowptr[node], end = rowptr[node + 1];
    int i = beg;
    for (; i + 3 < end; i += 4) {
        int s0 = esrc[i], s1 = esrc[i + 1], s2 = esrc[i + 2], s3 = esrc[i + 3];
        uint4 v0 = *((const uint4*)(h2b + (size_t)s0 * 16) + q);
        uint4 v1 = *((const uint4*)(h2b + (size_t)s1 * 16) + q);
        uint4 v2 = *((const uint4*)(h2b + (size_t)s2 * 16) + q);
        uint4 v3 = *((const uint4*)(h2b + (size_t)s3 * 16) + q);
        a0 += bflo(v0.x) + bflo(v1.x);
        a1 += bfhi(v0.x) + bfhi(v1.x);
        a2 += bflo(v0.y) + bflo(v1.y);
        a3 += bfhi(v0.y) + bfhi(v1.y);
        a4 += bflo(v0.z) + bflo(v1.z);
        a5 += bfhi(v0.z) + bfhi(v1.z);
        a6 += bflo(v0.w) + bflo(v1.w);
        a7 += bfhi(v0.w) + bfhi(v1.w);
        a0 += bflo(v2.x) + bflo(v3.x);
        a1 += bfhi(v2.x) + bfhi(v3.x);
        a2 += bflo(v2.y) + bflo(v3.y);
        a3 += bfhi(v2.y) + bfhi(v3.y);
        a4 += bflo(v2.z) + bflo(v3.z);
        a5 += bfhi(v2.z) + bfhi(v3.z);
        a6 += bflo(v2.w) + bflo(v3.w);
        a7 += bfhi(v2.w) + bfhi(v3.w);
    }
    for (; i < end; ++i) {
        uint4 v0 = *((const uint4*)(h2b + (size_t)esrc[i] * 16) + q);
        a0 += bflo(v0.x); a1 += bfhi(v0.x);
        a2 += bflo(v0.y); a3 += bfhi(v0.y);
        a4 += bflo(v0.z); a5 += bfhi(v0.z);
        a6 += bflo(v0.w); a7 += bfhi(v0.w);
    }
    float dv = dinv[node];
    float* orow = out + (size_t)node * NOUT;
    int col = q * 8;
    float av[8] = {a0, a1, a2, a3, a4, a5, a6, a7};
#pragma unroll
    for (int j = 0; j < 8; ++j)
        if (col + j < NOUT) orow[col + j] = fmaf(dv, av[j], b2[col + j]);
}

// ================= launch =================

extern "C" void kernel_launch(void* const* d_in, const int* in_sizes, int n_in,
                              void* d_out, int out_size, void* d_ws, size_t ws_size,
                              hipStream_t stream) {
    const float* x  = (const float*)d_in[0];
    const int*   ei = (const int*)d_in[1];
    const float* W1 = (const float*)d_in[2];
    const float* b1 = (const float*)d_in[3];
    const float* W2 = (const float*)d_in[4];
    const float* b2 = (const float*)d_in[5];
    float* out = (float*)d_out;

    int N = in_sizes[0] / NFEAT;
    int E = in_sizes[1] / 2;
    const int* src = ei;
    const int* dst = ei + E;
    int NBUK = (N + (1 << BSH) - 1) >> BSH;
    int NCHUNK = (E + CHUNK - 1) / CHUNK;

    char* p = (char*)d_ws;
    auto alloc = [&](size_t bytes) { void* r = (void*)p; p += (bytes + 255) & ~(size_t)255; return r; };
    int*   rowptr = (int*)alloc((size_t)(N + 1) * 4);
    int*   gcnt   = (int*)alloc((size_t)NBUK * PADI * 4);
    int*   bbase  = (int*)alloc((size_t)NBUK * 4);
    int*   tab    = (int*)alloc((size_t)NCHUNK * (NBUK + 1) * 4);
    uint*  ebuf   = (uint*)alloc((size_t)E * 4);
    int*   esrc   = (int*)alloc((size_t)E * 4);
    float* dinv   = (float*)alloc((size_t)N * 4);
    uint*  hb     = (uint*)alloc((size_t)N * 32 * 4);
    float* o1     = (float*)alloc((size_t)N * NHID * 4);
    uint*  h2b    = (uint*)alloc((size_t)N * 16 * 4);   // bf16 rows padded to 64 B
    int*   cnt    = (int*)alloc((size_t)N * 4);      // fallback only
    int*   fill   = (int*)alloc((size_t)N * 4);      // fallback only
    int*   bsum   = (int*)alloc(128 * 4);            // fallback only

    const int B = 256;

    if (N <= (1 << 17)) {
        hipMemsetAsync(gcnt, 0, (size_t)NBUK * PADI * 4, stream);
        k_lsort <<<NCHUNK, 256, 0, stream>>>(src, dst, ebuf, tab, gcnt, E, NBUK);
        k_bscan <<<1, 256, 0, stream>>>(gcnt, bbase, rowptr, NBUK, N, E);
        k_bsort2<<<NBUK, 256, 0, stream>>>(ebuf, tab, bbase, gcnt, rowptr, dinv, esrc, NCHUNK, NBUK, N);
    } else {
        int nb = (N + 1023) / 1024;
        hipMemsetAsync(cnt, 0, (size_t)N * 4, stream);
        k_count <<<(E + B - 1) / B, B, 0, stream>>>(dst, cnt, E);
        k_scan1 <<<nb, 256, 0, stream>>>(cnt, rowptr, bsum, dinv, N);
        k_scan2 <<<1, 128, 0, stream>>>(bsum, nb);
        k_scan3 <<<nb, 256, 0, stream>>>(rowptr, fill, bsum, N, E);
        k_scatter_direct<<<(E + B - 1) / B, B, 0, stream>>>(src, dst, fill, esrc, E);
    }

    k_gemm1 <<<(N + 63) / 64, 256, 0, stream>>>(x, W1, dinv, hb, N);
    k_agg1  <<<(N + 3) / 4, 256, 0, stream>>>(rowptr, esrc, hb, dinv, b1, o1, N);
    k_gemm2 <<<(N + 127) / 128, 128, 0, stream>>>(o1, W2, dinv, h2b, N);
    k_agg2  <<<(N + 63) / 64, 256, 0, stream>>>(rowptr, esrc, h2b, dinv, b2, out, N);
}